// Round 1
// baseline (724.910 us; speedup 1.0000x reference)
//
#include <hip/hip_runtime.h>
#include <math.h>

#define BB 32
#define SS 4096
#define DHH 512
#define EHH 512
#define AA 256

// K1: dec_proj[b][a] = sum_e h[b][e] * Wd[e][a]
__global__ __launch_bounds__(256) void k_decproj(const float* __restrict__ h,
                                                 const float* __restrict__ Wd,
                                                 float* __restrict__ dp) {
    int b = blockIdx.x;
    int a = threadIdx.x;
    float acc = 0.f;
    for (int e = 0; e < DHH; ++e)
        acc = fmaf(h[b * DHH + e], Wd[e * AA + a], acc);
    dp[b * AA + a] = acc;
}

// K2: energy[b][s] = sum_a v[a] * tanh(dp[b][a] + sum_e enc[b][s][e]*We[e][a])
// Block: 256 threads = 4 waves. Wave ty owns rows 4*ty..4*ty+3 (complete rows).
// Thread tx (0..63) owns cols 4*tx..4*tx+3. 16 rows/block staged in LDS.
__global__ __launch_bounds__(256) void k_energy(const float* __restrict__ enc,
                                                const float* __restrict__ We,
                                                const float* __restrict__ dp,
                                                const float* __restrict__ v,
                                                float* __restrict__ energy) {
    __shared__ float lds[16][EHH];  // 32 KB
    int tile = blockIdx.x;                 // B*S/16 = 8192 tiles
    int b = tile / (SS / 16);
    int s0 = (tile % (SS / 16)) * 16;
    int tid = threadIdx.x;
    int tx = tid & 63;
    int ty = tid >> 6;

    // stage 16 encoder rows (contiguous 32 KB), float4 coalesced
    const float4* src = (const float4*)(enc + ((size_t)b * SS + s0) * EHH);
    float4* ldsf4 = (float4*)&lds[0][0];
    #pragma unroll
    for (int k = 0; k < 8; ++k)
        ldsf4[tid + 256 * k] = src[tid + 256 * k];
    __syncthreads();

    float acc[4][4];
    #pragma unroll
    for (int i = 0; i < 4; ++i)
        #pragma unroll
        for (int j = 0; j < 4; ++j) acc[i][j] = 0.f;

    const float4* Wep = (const float4*)We;  // We[e][4*tx+j] = Wep[e*64+tx].j
    for (int e = 0; e < EHH; e += 4) {
        float wk[4][4];
        #pragma unroll
        for (int k = 0; k < 4; ++k) {
            float4 t = Wep[(size_t)(e + k) * 64 + tx];
            wk[k][0] = t.x; wk[k][1] = t.y; wk[k][2] = t.z; wk[k][3] = t.w;
        }
        float ea[4][4];
        #pragma unroll
        for (int i = 0; i < 4; ++i) {
            float4 t = *(const float4*)&lds[4 * ty + i][e];
            ea[i][0] = t.x; ea[i][1] = t.y; ea[i][2] = t.z; ea[i][3] = t.w;
        }
        #pragma unroll
        for (int i = 0; i < 4; ++i)
            #pragma unroll
            for (int j = 0; j < 4; ++j)
                #pragma unroll
                for (int k = 0; k < 4; ++k)
                    acc[i][j] = fmaf(ea[i][k], wk[k][j], acc[i][j]);
    }

    float4 dpv = *(const float4*)&dp[b * AA + 4 * tx];
    float4 vv = *(const float4*)&v[4 * tx];
    #pragma unroll
    for (int i = 0; i < 4; ++i) {
        float t = tanhf(acc[i][0] + dpv.x) * vv.x
                + tanhf(acc[i][1] + dpv.y) * vv.y
                + tanhf(acc[i][2] + dpv.z) * vv.z
                + tanhf(acc[i][3] + dpv.w) * vv.w;
        #pragma unroll
        for (int o = 32; o; o >>= 1) t += __shfl_down(t, o);
        if (tx == 0) energy[(size_t)b * SS + s0 + 4 * ty + i] = t;
    }
}

// K3: masked softmax over S per batch row; nan_to_num -> zeros when all masked
__global__ __launch_bounds__(1024) void k_softmax(const float* __restrict__ energy,
                                                  const int* __restrict__ mask,
                                                  float* __restrict__ attn) {
    __shared__ float se[SS];   // 16 KB
    __shared__ float w1[16];
    __shared__ float w2[16];
    int b = blockIdx.x;
    int tid = threadIdx.x;
    int lane = tid & 63, wv = tid >> 6;
    const float* eb = energy + (size_t)b * SS;
    const int* mb = mask + (size_t)b * SS;

    float lmax = -INFINITY;
    for (int s = tid; s < SS; s += 1024) {
        float e = mb[s] ? eb[s] : -INFINITY;
        se[s] = e;
        lmax = fmaxf(lmax, e);
    }
    #pragma unroll
    for (int o = 32; o; o >>= 1) lmax = fmaxf(lmax, __shfl_down(lmax, o));
    if (!lane) w1[wv] = lmax;
    __syncthreads();
    float m = w1[0];
    #pragma unroll
    for (int i = 1; i < 16; ++i) m = fmaxf(m, w1[i]);

    float lsum = 0.f;
    for (int s = tid; s < SS; s += 1024) {
        float ev = se[s];
        float p = (ev == -INFINITY) ? 0.f : expf(ev - m);
        se[s] = p;
        lsum += p;
    }
    #pragma unroll
    for (int o = 32; o; o >>= 1) lsum += __shfl_down(lsum, o);
    if (!lane) w2[wv] = lsum;
    __syncthreads();
    float tot = 0.f;
    #pragma unroll
    for (int i = 0; i < 16; ++i) tot += w2[i];
    float inv = tot > 0.f ? 1.0f / tot : 0.f;
    float* ab = attn + (size_t)b * SS;
    for (int s = tid; s < SS; s += 1024) ab[s] = se[s] * inv;
}

// K4a: partial context: block (b, c) sums S/16 rows
__global__ __launch_bounds__(512) void k_ctx_partial(const float* __restrict__ enc,
                                                     const float* __restrict__ attn,
                                                     float* __restrict__ partial) {
    int b = blockIdx.x, c = blockIdx.y;
    int e = threadIdx.x;
    int s0 = c * (SS / 16);
    const float* ab = attn + (size_t)b * SS + s0;
    const float* eb = enc + ((size_t)b * SS + s0) * EHH + e;
    float acc = 0.f;
    #pragma unroll 4
    for (int s = 0; s < SS / 16; ++s)
        acc = fmaf(ab[s], eb[(size_t)s * EHH], acc);
    partial[((size_t)b * 16 + c) * EHH + e] = acc;
}

// K4b: reduce 16 partials
__global__ __launch_bounds__(512) void k_ctx_reduce(const float* __restrict__ partial,
                                                    float* __restrict__ ctx) {
    int b = blockIdx.x;
    int e = threadIdx.x;
    float acc = 0.f;
    #pragma unroll
    for (int c = 0; c < 16; ++c)
        acc += partial[((size_t)b * 16 + c) * EHH + e];
    ctx[(size_t)b * EHH + e] = acc;
}

extern "C" void kernel_launch(void* const* d_in, const int* in_sizes, int n_in,
                              void* d_out, int out_size, void* d_ws, size_t ws_size,
                              hipStream_t stream) {
    const float* h    = (const float*)d_in[0];
    const float* enc  = (const float*)d_in[1];
    const int*   mask = (const int*)d_in[2];
    const float* Wd   = (const float*)d_in[3];
    const float* We   = (const float*)d_in[4];
    const float* v    = (const float*)d_in[5];

    float* out  = (float*)d_out;
    float* ctx  = out;              // (B, EH) = 16384 floats
    float* attn = out + BB * EHH;   // (B, S)  = 131072 floats

    char* ws = (char*)d_ws;
    float* dp      = (float*)ws;                    // 32 KB
    float* energy  = (float*)(ws + 32768);          // 512 KB
    float* partial = (float*)(ws + 32768 + 524288); // 1 MB

    k_decproj<<<BB, AA, 0, stream>>>(h, Wd, dp);
    k_energy<<<BB * SS / 16, 256, 0, stream>>>(enc, We, dp, v, energy);
    k_softmax<<<BB, 1024, 0, stream>>>(energy, mask, attn);
    k_ctx_partial<<<dim3(BB, 16), 512, 0, stream>>>(enc, attn, partial);
    k_ctx_reduce<<<BB, 512, 0, stream>>>(partial, ctx);
}

// Round 2
// 248.172 us; speedup vs baseline: 2.9210x; 2.9210x over previous
//
#include <hip/hip_runtime.h>
#include <math.h>

#define BB 32
#define SS 4096
#define DHH 512
#define EHH 512
#define AA 256

typedef __attribute__((ext_vector_type(8))) short bf16x8;
typedef __attribute__((ext_vector_type(4))) float f32x4;

__device__ __forceinline__ short f2bf(float f) {
    unsigned u = __float_as_uint(f);
    u += 0x7FFFu + ((u >> 16) & 1u);   // RNE
    return (short)(u >> 16);
}

__device__ __forceinline__ float tanh_fast(float x) {
    float e = __expf(2.0f * x);                       // v_exp_f32
    return 1.0f - 2.0f * __builtin_amdgcn_rcpf(e + 1.0f);
}

// K0: pack We (E,A) fp32 -> Wt (A,E) bf16 so B-fragments are contiguous-k 16B loads
__global__ __launch_bounds__(512) void k_packWe(const float* __restrict__ We,
                                                unsigned short* __restrict__ Wt) {
    int a = blockIdx.x;       // 0..255
    int e = threadIdx.x;      // 0..511
    Wt[(size_t)a * EHH + e] = (unsigned short)f2bf(We[(size_t)e * AA + a]);
}

// K1: dec_proj[b][a] = sum_e h[b][e] * Wd[e][a]  (fp32, tiny)
__global__ __launch_bounds__(256) void k_decproj(const float* __restrict__ h,
                                                 const float* __restrict__ Wd,
                                                 float* __restrict__ dp) {
    int b = blockIdx.x;
    int a = threadIdx.x;
    float acc = 0.f;
    for (int e = 0; e < DHH; ++e)
        acc = fmaf(h[b * DHH + e], Wd[e * AA + a], acc);
    dp[b * AA + a] = acc;
}

// K2: energy via bf16 MFMA. Block=256 (4 waves), each wave: 32 rows (2 row-tiles
// of 16) x 256 cols (16 col-tiles), K=512 (16 k-steps of 32).
// A frag: lane holds enc[row = l&15][k = 8*(l>>4)+j] (8 contiguous k, cvt fp32->bf16)
// B frag: lane holds We[k = 8*(l>>4)+j][n = l&15] via Wt[n][k] contiguous load
// D: row = 4*(l>>4)+r, col = l&15
__global__ __launch_bounds__(256) void k_energy_mfma(const float* __restrict__ enc,
                                                     const unsigned short* __restrict__ Wt,
                                                     const float* __restrict__ dp,
                                                     const float* __restrict__ v,
                                                     float* __restrict__ energy) {
    int bk = blockIdx.x;            // 1024 blocks
    int b  = bk >> 5;               // 32 blocks per batch row
    int s0 = (bk & 31) * 128;
    int tid = threadIdx.x;
    int l  = tid & 63;
    int w  = tid >> 6;
    int lo = l & 15;
    int hi = l >> 4;

    int srow = s0 + w * 32;

    f32x4 acc[2][16];
    #pragma unroll
    for (int rt = 0; rt < 2; ++rt)
        #pragma unroll
        for (int ct = 0; ct < 16; ++ct)
            acc[rt][ct] = (f32x4){0.f, 0.f, 0.f, 0.f};

    const float* pa0 = enc + ((size_t)(b * SS + srow + lo)) * EHH + 8 * hi;
    const float* pa1 = pa0 + (size_t)16 * EHH;
    const unsigned short* pb0 = Wt + (size_t)lo * EHH + 8 * hi;

    for (int kt = 0; kt < 16; ++kt) {
        int ko = kt * 32;
        float4 a0l = *(const float4*)(pa0 + ko);
        float4 a0h = *(const float4*)(pa0 + ko + 4);
        float4 a1l = *(const float4*)(pa1 + ko);
        float4 a1h = *(const float4*)(pa1 + ko + 4);
        bf16x8 af0, af1;
        af0[0] = f2bf(a0l.x); af0[1] = f2bf(a0l.y); af0[2] = f2bf(a0l.z); af0[3] = f2bf(a0l.w);
        af0[4] = f2bf(a0h.x); af0[5] = f2bf(a0h.y); af0[6] = f2bf(a0h.z); af0[7] = f2bf(a0h.w);
        af1[0] = f2bf(a1l.x); af1[1] = f2bf(a1l.y); af1[2] = f2bf(a1l.z); af1[3] = f2bf(a1l.w);
        af1[4] = f2bf(a1h.x); af1[5] = f2bf(a1h.y); af1[6] = f2bf(a1h.z); af1[7] = f2bf(a1h.w);
        #pragma unroll
        for (int ct = 0; ct < 16; ++ct) {
            bf16x8 bf = *(const bf16x8*)(pb0 + ko + (size_t)ct * 16 * EHH);
            acc[0][ct] = __builtin_amdgcn_mfma_f32_16x16x32_bf16(af0, bf, acc[0][ct], 0, 0, 0);
            acc[1][ct] = __builtin_amdgcn_mfma_f32_16x16x32_bf16(af1, bf, acc[1][ct], 0, 0, 0);
        }
    }

    // epilogue: energy[row] = sum_n v[n] * tanh(acc + dp[b][n])
    float ps[2][4] = {{0.f, 0.f, 0.f, 0.f}, {0.f, 0.f, 0.f, 0.f}};
    #pragma unroll
    for (int ct = 0; ct < 16; ++ct) {
        float dpv = dp[b * AA + ct * 16 + lo];
        float vv  = v[ct * 16 + lo];
        #pragma unroll
        for (int rt = 0; rt < 2; ++rt)
            #pragma unroll
            for (int r = 0; r < 4; ++r)
                ps[rt][r] += vv * tanh_fast(acc[rt][ct][r] + dpv);
    }
    #pragma unroll
    for (int off = 1; off < 16; off <<= 1)
        #pragma unroll
        for (int rt = 0; rt < 2; ++rt)
            #pragma unroll
            for (int r = 0; r < 4; ++r)
                ps[rt][r] += __shfl_xor(ps[rt][r], off);
    if (lo == 0) {
        #pragma unroll
        for (int rt = 0; rt < 2; ++rt)
            #pragma unroll
            for (int r = 0; r < 4; ++r)
                energy[(size_t)b * SS + srow + rt * 16 + 4 * hi + r] = ps[rt][r];
    }
}

// K3: masked softmax over S per batch row; nan_to_num -> zeros when all masked
__global__ __launch_bounds__(1024) void k_softmax(const float* __restrict__ energy,
                                                  const int* __restrict__ mask,
                                                  float* __restrict__ attn) {
    __shared__ float se[SS];
    __shared__ float w1[16];
    __shared__ float w2[16];
    int b = blockIdx.x;
    int tid = threadIdx.x;
    int lane = tid & 63, wv = tid >> 6;
    const float* eb = energy + (size_t)b * SS;
    const int* mb = mask + (size_t)b * SS;

    float lmax = -INFINITY;
    for (int s = tid; s < SS; s += 1024) {
        float e = mb[s] ? eb[s] : -INFINITY;
        se[s] = e;
        lmax = fmaxf(lmax, e);
    }
    #pragma unroll
    for (int o = 32; o; o >>= 1) lmax = fmaxf(lmax, __shfl_down(lmax, o));
    if (!lane) w1[wv] = lmax;
    __syncthreads();
    float m = w1[0];
    #pragma unroll
    for (int i = 1; i < 16; ++i) m = fmaxf(m, w1[i]);

    float lsum = 0.f;
    for (int s = tid; s < SS; s += 1024) {
        float ev = se[s];
        float p = (ev == -INFINITY) ? 0.f : expf(ev - m);
        se[s] = p;
        lsum += p;
    }
    #pragma unroll
    for (int o = 32; o; o >>= 1) lsum += __shfl_down(lsum, o);
    if (!lane) w2[wv] = lsum;
    __syncthreads();
    float tot = 0.f;
    #pragma unroll
    for (int i = 0; i < 16; ++i) tot += w2[i];
    float inv = tot > 0.f ? 1.0f / tot : 0.f;
    float* ab = attn + (size_t)b * SS;
    for (int s = tid; s < SS; s += 1024) ab[s] = se[s] * inv;
}

// K4a: partial context: block (b, c) sums S/16 rows
__global__ __launch_bounds__(512) void k_ctx_partial(const float* __restrict__ enc,
                                                     const float* __restrict__ attn,
                                                     float* __restrict__ partial) {
    int b = blockIdx.x, c = blockIdx.y;
    int e = threadIdx.x;
    int s0 = c * (SS / 16);
    const float* ab = attn + (size_t)b * SS + s0;
    const float* eb = enc + ((size_t)b * SS + s0) * EHH + e;
    float acc = 0.f;
    #pragma unroll 4
    for (int s = 0; s < SS / 16; ++s)
        acc = fmaf(ab[s], eb[(size_t)s * EHH], acc);
    partial[((size_t)b * 16 + c) * EHH + e] = acc;
}

// K4b: reduce 16 partials
__global__ __launch_bounds__(512) void k_ctx_reduce(const float* __restrict__ partial,
                                                    float* __restrict__ ctx) {
    int b = blockIdx.x;
    int e = threadIdx.x;
    float acc = 0.f;
    #pragma unroll
    for (int c = 0; c < 16; ++c)
        acc += partial[((size_t)b * 16 + c) * EHH + e];
    ctx[(size_t)b * EHH + e] = acc;
}

extern "C" void kernel_launch(void* const* d_in, const int* in_sizes, int n_in,
                              void* d_out, int out_size, void* d_ws, size_t ws_size,
                              hipStream_t stream) {
    const float* h    = (const float*)d_in[0];
    const float* enc  = (const float*)d_in[1];
    const int*   mask = (const int*)d_in[2];
    const float* Wd   = (const float*)d_in[3];
    const float* We   = (const float*)d_in[4];
    const float* v    = (const float*)d_in[5];

    float* out  = (float*)d_out;
    float* ctx  = out;              // (B, EH)
    float* attn = out + BB * EHH;   // (B, S)

    char* ws = (char*)d_ws;
    float* dp      = (float*)ws;                     // 32 KB
    float* energy  = (float*)(ws + 32768);           // 512 KB
    float* partial = (float*)(ws + 32768 + 524288);  // 1 MB
    // Wt aliases the first 256 KB of `partial`: Wt is dead before k_ctx_partial
    // writes partial, and k_packWe rewrites Wt at the start of every launch.
    unsigned short* Wt = (unsigned short*)(ws + 32768 + 524288);

    k_packWe<<<AA, 512, 0, stream>>>(We, Wt);
    k_decproj<<<BB, AA, 0, stream>>>(h, Wd, dp);
    k_energy_mfma<<<BB * SS / 128, 256, 0, stream>>>(enc, Wt, dp, v, energy);
    k_softmax<<<BB, 1024, 0, stream>>>(energy, mask, attn);
    k_ctx_partial<<<dim3(BB, 16), 512, 0, stream>>>(enc, attn, partial);
    k_ctx_reduce<<<BB, 512, 0, stream>>>(partial, ctx);
}

// Round 3
// 244.226 us; speedup vs baseline: 2.9682x; 1.0162x over previous
//
#include <hip/hip_runtime.h>
#include <hip/hip_bf16.h>
#include <math.h>

#define BB 32
#define SS 4096
#define DHH 512
#define EHH 512
#define AA 256

typedef __attribute__((ext_vector_type(8))) short bf16x8;
typedef __attribute__((ext_vector_type(4))) float f32x4;

__device__ __forceinline__ short f2bf(float f) {
    unsigned u = __float_as_uint(f);
    u += 0x7FFFu + ((u >> 16) & 1u);   // RNE
    return (short)(u >> 16);
}

__device__ __forceinline__ unsigned cvt2bf(float a, float b) {
    __hip_bfloat162 h = __float22bfloat162_rn(float2{a, b});  // v_cvt_pk_bf16_f32
    return *(unsigned*)&h;
}

__device__ __forceinline__ float tanh_fast(float x) {
    float e = __expf(2.0f * x);
    return 1.0f - 2.0f * __builtin_amdgcn_rcpf(e + 1.0f);
}

// K0: pack We (E,A) fp32 -> Wt (A,E) bf16 (B-fragments become contiguous 16B loads)
__global__ __launch_bounds__(512) void k_packWe(const float* __restrict__ We,
                                                unsigned short* __restrict__ Wt) {
    int a = blockIdx.x;
    int e = threadIdx.x;
    Wt[(size_t)a * EHH + e] = (unsigned short)f2bf(We[(size_t)e * AA + a]);
}

// K1: dec_proj (tiny fp32)
__global__ __launch_bounds__(256) void k_decproj(const float* __restrict__ h,
                                                 const float* __restrict__ Wd,
                                                 float* __restrict__ dp) {
    int b = blockIdx.x;
    int a = threadIdx.x;
    float acc = 0.f;
    for (int e = 0; e < DHH; ++e)
        acc = fmaf(h[b * DHH + e], Wd[e * AA + a], acc);
    dp[b * AA + a] = acc;
}

// K2: energy GEMM. Block = 256 thr (4 waves), tile 64 rows x 256 cols, K=512.
// Wave w: rows (w&1)*32 .. +32 (2 row-tiles), cols (w>>1)*128 .. +128 (8 col-tiles).
// A (enc fp32) staged to LDS as bf16 (cvt at staging), XOR-swizzled, double-buffered
// over BK=64 K-steps. B (Wt bf16) direct from L2.
__global__ __launch_bounds__(256) void k_energy_mfma(const float* __restrict__ enc,
                                                     const unsigned short* __restrict__ Wt,
                                                     const float* __restrict__ dp,
                                                     const float* __restrict__ v,
                                                     float* __restrict__ energy) {
    __shared__ unsigned short Abuf[2][64 * 64];   // 2 x 8 KB bf16, swizzled
    __shared__ float part[2][64];

    int bk = blockIdx.x;            // 2048 blocks
    int b  = bk >> 6;               // 64 blocks per batch row
    int s0 = (bk & 63) * 64;
    int tid = threadIdx.x;
    int l  = tid & 63;
    int w  = tid >> 6;
    int lo = l & 15;
    int hi = l >> 4;

    int rowbase = (w & 1) * 32;     // wave's rows within tile
    int colbase = (w >> 1) * 128;   // wave's cols

    // staging role: thread t -> tile row r = t>>2, quarter q = t&3 (16 fp32 cols)
    int r = tid >> 2;
    int q = tid & 3;
    const float* gbase = enc + ((size_t)b * SS + s0 + r) * EHH + q * 16;
    int wbyte0 = ((r * 128 + q * 32) ^ ((r & 7) << 4));
    int wbyte1 = ((r * 128 + q * 32 + 16) ^ ((r & 7) << 4));

    f32x4 acc[2][8];
    #pragma unroll
    for (int rt = 0; rt < 2; ++rt)
        #pragma unroll
        for (int ct = 0; ct < 8; ++ct)
            acc[rt][ct] = (f32x4){0.f, 0.f, 0.f, 0.f};

    // ---- prologue: stage kt=0 ----
    float4 s0v, s1v, s2v, s3v;
    {
        const float4* gp = (const float4*)gbase;
        s0v = gp[0]; s1v = gp[1]; s2v = gp[2]; s3v = gp[3];
        uint4 w0 = { cvt2bf(s0v.x, s0v.y), cvt2bf(s0v.z, s0v.w),
                     cvt2bf(s1v.x, s1v.y), cvt2bf(s1v.z, s1v.w) };
        uint4 w1 = { cvt2bf(s2v.x, s2v.y), cvt2bf(s2v.z, s2v.w),
                     cvt2bf(s3v.x, s3v.y), cvt2bf(s3v.z, s3v.w) };
        char* lb = (char*)Abuf[0];
        *(uint4*)(lb + wbyte0) = w0;
        *(uint4*)(lb + wbyte1) = w1;
    }
    __syncthreads();

    const unsigned short* Wtp = Wt + (size_t)(colbase + lo) * EHH;  // + ct*16*EHH

    for (int kt = 0; kt < 8; ++kt) {
        // issue next K-step's global loads early (latency hides under compute)
        if (kt < 7) {
            const float4* gp = (const float4*)(gbase + (kt + 1) * 64);
            s0v = gp[0]; s1v = gp[1]; s2v = gp[2]; s3v = gp[3];
        }

        // compute current buffer
        const char* lb = (const char*)Abuf[kt & 1];
        #pragma unroll
        for (int ks = 0; ks < 2; ++ks) {
            bf16x8 bf[8];
            #pragma unroll
            for (int ct = 0; ct < 8; ++ct)
                bf[ct] = *(const bf16x8*)(Wtp + (size_t)ct * 16 * EHH + kt * 64 + ks * 32 + hi * 8);
            int row0 = rowbase + lo;
            int row1 = rowbase + 16 + lo;
            bf16x8 a0 = *(const bf16x8*)(lb + ((row0 * 128 + ks * 64 + hi * 16) ^ ((row0 & 7) << 4)));
            bf16x8 a1 = *(const bf16x8*)(lb + ((row1 * 128 + ks * 64 + hi * 16) ^ ((row1 & 7) << 4)));
            #pragma unroll
            for (int ct = 0; ct < 8; ++ct) {
                acc[0][ct] = __builtin_amdgcn_mfma_f32_16x16x32_bf16(a0, bf[ct], acc[0][ct], 0, 0, 0);
                acc[1][ct] = __builtin_amdgcn_mfma_f32_16x16x32_bf16(a1, bf[ct], acc[1][ct], 0, 0, 0);
            }
        }

        // write next buffer (nobody reads it this iteration)
        if (kt < 7) {
            uint4 w0 = { cvt2bf(s0v.x, s0v.y), cvt2bf(s0v.z, s0v.w),
                         cvt2bf(s1v.x, s1v.y), cvt2bf(s1v.z, s1v.w) };
            uint4 w1 = { cvt2bf(s2v.x, s2v.y), cvt2bf(s2v.z, s2v.w),
                         cvt2bf(s3v.x, s3v.y), cvt2bf(s3v.z, s3v.w) };
            char* lbw = (char*)Abuf[(kt + 1) & 1];
            *(uint4*)(lbw + wbyte0) = w0;
            *(uint4*)(lbw + wbyte1) = w1;
        }
        __syncthreads();
    }

    // ---- epilogue: energy[row] = sum_n v[n] * tanh(acc + dp[b][n]) ----
    float ps[2][4] = {{0.f, 0.f, 0.f, 0.f}, {0.f, 0.f, 0.f, 0.f}};
    #pragma unroll
    for (int ct = 0; ct < 8; ++ct) {
        int n = colbase + ct * 16 + lo;
        float dpv = dp[b * AA + n];
        float vv  = v[n];
        #pragma unroll
        for (int rt = 0; rt < 2; ++rt)
            #pragma unroll
            for (int rr = 0; rr < 4; ++rr)
                ps[rt][rr] += vv * tanh_fast(acc[rt][ct][rr] + dpv);
    }
    #pragma unroll
    for (int off = 1; off < 16; off <<= 1)
        #pragma unroll
        for (int rt = 0; rt < 2; ++rt)
            #pragma unroll
            for (int rr = 0; rr < 4; ++rr)
                ps[rt][rr] += __shfl_xor(ps[rt][rr], off);
    if (lo == 0) {
        #pragma unroll
        for (int rt = 0; rt < 2; ++rt)
            #pragma unroll
            for (int rr = 0; rr < 4; ++rr)
                part[w >> 1][rowbase + rt * 16 + 4 * hi + rr] = ps[rt][rr];
    }
    __syncthreads();
    if (tid < 64)
        energy[(size_t)b * SS + s0 + tid] = part[0][tid] + part[1][tid];
}

// K3: masked softmax over S per batch row; nan_to_num -> zeros when all masked
__global__ __launch_bounds__(1024) void k_softmax(const float* __restrict__ energy,
                                                  const int* __restrict__ mask,
                                                  float* __restrict__ attn) {
    __shared__ float se[SS];
    __shared__ float w1[16];
    __shared__ float w2[16];
    int b = blockIdx.x;
    int tid = threadIdx.x;
    int lane = tid & 63, wv = tid >> 6;
    const float* eb = energy + (size_t)b * SS;
    const int* mb = mask + (size_t)b * SS;

    float lmax = -INFINITY;
    for (int s = tid; s < SS; s += 1024) {
        float e = mb[s] ? eb[s] : -INFINITY;
        se[s] = e;
        lmax = fmaxf(lmax, e);
    }
    #pragma unroll
    for (int o = 32; o; o >>= 1) lmax = fmaxf(lmax, __shfl_down(lmax, o));
    if (!lane) w1[wv] = lmax;
    __syncthreads();
    float m = w1[0];
    #pragma unroll
    for (int i = 1; i < 16; ++i) m = fmaxf(m, w1[i]);

    float lsum = 0.f;
    for (int s = tid; s < SS; s += 1024) {
        float ev = se[s];
        float p = (ev == -INFINITY) ? 0.f : expf(ev - m);
        se[s] = p;
        lsum += p;
    }
    #pragma unroll
    for (int o = 32; o; o >>= 1) lsum += __shfl_down(lsum, o);
    if (!lane) w2[wv] = lsum;
    __syncthreads();
    float tot = 0.f;
    #pragma unroll
    for (int i = 0; i < 16; ++i) tot += w2[i];
    float inv = tot > 0.f ? 1.0f / tot : 0.f;
    float* ab = attn + (size_t)b * SS;
    for (int s = tid; s < SS; s += 1024) ab[s] = se[s] * inv;
}

// K4a: partial context
__global__ __launch_bounds__(512) void k_ctx_partial(const float* __restrict__ enc,
                                                     const float* __restrict__ attn,
                                                     float* __restrict__ partial) {
    int b = blockIdx.x, c = blockIdx.y;
    int e = threadIdx.x;
    int s0 = c * (SS / 16);
    const float* ab = attn + (size_t)b * SS + s0;
    const float* eb = enc + ((size_t)b * SS + s0) * EHH + e;
    float acc = 0.f;
    #pragma unroll 4
    for (int s = 0; s < SS / 16; ++s)
        acc = fmaf(ab[s], eb[(size_t)s * EHH], acc);
    partial[((size_t)b * 16 + c) * EHH + e] = acc;
}

// K4b: reduce 16 partials
__global__ __launch_bounds__(512) void k_ctx_reduce(const float* __restrict__ partial,
                                                    float* __restrict__ ctx) {
    int b = blockIdx.x;
    int e = threadIdx.x;
    float acc = 0.f;
    #pragma unroll
    for (int c = 0; c < 16; ++c)
        acc += partial[((size_t)b * 16 + c) * EHH + e];
    ctx[(size_t)b * EHH + e] = acc;
}

extern "C" void kernel_launch(void* const* d_in, const int* in_sizes, int n_in,
                              void* d_out, int out_size, void* d_ws, size_t ws_size,
                              hipStream_t stream) {
    const float* h    = (const float*)d_in[0];
    const float* enc  = (const float*)d_in[1];
    const int*   mask = (const int*)d_in[2];
    const float* Wd   = (const float*)d_in[3];
    const float* We   = (const float*)d_in[4];
    const float* v    = (const float*)d_in[5];

    float* out  = (float*)d_out;
    float* ctx  = out;              // (B, EH)
    float* attn = out + BB * EHH;   // (B, S)

    char* ws = (char*)d_ws;
    float* dp      = (float*)ws;                     // 32 KB
    float* energy  = (float*)(ws + 32768);           // 512 KB
    float* partial = (float*)(ws + 32768 + 524288);  // 1 MB
    // Wt aliases partial: Wt dead before k_ctx_partial writes; rewritten each launch
    unsigned short* Wt = (unsigned short*)(ws + 32768 + 524288);

    k_packWe<<<AA, 512, 0, stream>>>(We, Wt);
    k_decproj<<<BB, AA, 0, stream>>>(h, Wd, dp);
    k_energy_mfma<<<BB * SS / 64, 256, 0, stream>>>(enc, Wt, dp, v, energy);
    k_softmax<<<BB, 1024, 0, stream>>>(energy, mask, attn);
    k_ctx_partial<<<dim3(BB, 16), 512, 0, stream>>>(enc, attn, partial);
    k_ctx_reduce<<<BB, 512, 0, stream>>>(partial, ctx);
}

// Round 4
// 169.463 us; speedup vs baseline: 4.2777x; 1.4412x over previous
//
#include <hip/hip_runtime.h>
#include <hip/hip_bf16.h>
#include <math.h>

#define BB 32
#define SS 4096
#define DHH 512
#define EHH 512
#define AA 256

typedef __attribute__((ext_vector_type(8))) short bf16x8;
typedef __attribute__((ext_vector_type(4))) float f32x4;

__device__ __forceinline__ short f2bf(float f) {
    unsigned u = __float_as_uint(f);
    u += 0x7FFFu + ((u >> 16) & 1u);   // RNE
    return (short)(u >> 16);
}

__device__ __forceinline__ unsigned cvt2bf(float a, float b) {
    __hip_bfloat162 h = __float22bfloat162_rn(float2{a, b});  // v_cvt_pk_bf16_f32
    return *(unsigned*)&h;
}

__device__ __forceinline__ float tanh_fast(float x) {
    float e = __expf(2.0f * x);
    return 1.0f - 2.0f * __builtin_amdgcn_rcpf(e + 1.0f);
}

// K0: pack We (E,A) fp32 -> fragment-major bf16:
// Wpack[((kk*16 + ct)*64 + hi*16 + lo)*8 + j] = We[k][n],
//   k = kk*32 + hi*8 + j, n = ct*16 + lo.
// B-loads in the GEMM become lane-linear (16B/lane, wave-contiguous 1KB).
__global__ __launch_bounds__(512) void k_packWe(const float* __restrict__ We,
                                                unsigned short* __restrict__ Wpack) {
    int a = blockIdx.x;       // n: 0..255
    int e = threadIdx.x;      // k: 0..511
    int kk = e >> 5, hi = (e >> 3) & 3, j = e & 7;
    int ct = a >> 4, lo = a & 15;
    size_t idx = ((size_t)((kk * 16 + ct) * 64 + hi * 16 + lo)) * 8 + j;
    Wpack[idx] = (unsigned short)f2bf(We[(size_t)e * AA + a]);
}

// K1: dec_proj (tiny fp32)
__global__ __launch_bounds__(256) void k_decproj(const float* __restrict__ h,
                                                 const float* __restrict__ Wd,
                                                 float* __restrict__ dp) {
    int b = blockIdx.x;
    int a = threadIdx.x;
    float acc = 0.f;
    for (int e = 0; e < DHH; ++e)
        acc = fmaf(h[b * DHH + e], Wd[e * AA + a], acc);
    dp[b * AA + a] = acc;
}

// K2: energy GEMM. Block = 256 thr (4 waves), tile 64 rows x 256 cols, K=512.
// Wave w: rows (w&1)*32..+32, cols (w>>1)*128..+128 (8 col-tiles).
// A: enc fp32 -> bf16 at staging, XOR-swizzled LDS, double-buffered BK=64.
// B: fragment-major Wpack, coalesced 16B/lane loads from L2.
__global__ __launch_bounds__(256) void k_energy_mfma(const float* __restrict__ enc,
                                                     const unsigned short* __restrict__ Wpack,
                                                     const float* __restrict__ dp,
                                                     const float* __restrict__ v,
                                                     float* __restrict__ energy) {
    __shared__ unsigned short Abuf[2][64 * 64];   // 2 x 8 KB bf16, swizzled
    __shared__ float part[2][64];

    int bk = blockIdx.x;            // 2048 blocks
    int b  = bk >> 6;
    int s0 = (bk & 63) * 64;
    int tid = threadIdx.x;
    int l  = tid & 63;
    int w  = tid >> 6;
    int lo = l & 15;
    int hi = l >> 4;

    int rowbase = (w & 1) * 32;
    int colbase8 = (w >> 1) * 8;    // col-tile base (8 tiles of 16)

    // staging role: thread t -> tile row r = t>>2, quarter q = t&3 (16 fp32 cols)
    int r = tid >> 2;
    int q = tid & 3;
    const float* gbase = enc + ((size_t)b * SS + s0 + r) * EHH + q * 16;
    int wbyte0 = ((r * 128 + q * 32) ^ ((r & 7) << 4));
    int wbyte1 = ((r * 128 + q * 32 + 16) ^ ((r & 7) << 4));

    f32x4 acc[2][8];
    #pragma unroll
    for (int rt = 0; rt < 2; ++rt)
        #pragma unroll
        for (int ct = 0; ct < 8; ++ct)
            acc[rt][ct] = (f32x4){0.f, 0.f, 0.f, 0.f};

    // ---- prologue: stage kt=0 ----
    float4 s0v, s1v, s2v, s3v;
    {
        const float4* gp = (const float4*)gbase;
        s0v = gp[0]; s1v = gp[1]; s2v = gp[2]; s3v = gp[3];
        uint4 w0 = { cvt2bf(s0v.x, s0v.y), cvt2bf(s0v.z, s0v.w),
                     cvt2bf(s1v.x, s1v.y), cvt2bf(s1v.z, s1v.w) };
        uint4 w1 = { cvt2bf(s2v.x, s2v.y), cvt2bf(s2v.z, s2v.w),
                     cvt2bf(s3v.x, s3v.y), cvt2bf(s3v.z, s3v.w) };
        char* lb = (char*)Abuf[0];
        *(uint4*)(lb + wbyte0) = w0;
        *(uint4*)(lb + wbyte1) = w1;
    }
    __syncthreads();

    // B fragment base: lane-linear within each (kk, ct) tile
    const unsigned short* bbase = Wpack + (size_t)l * 8;

    for (int kt = 0; kt < 8; ++kt) {
        if (kt < 7) {
            const float4* gp = (const float4*)(gbase + (kt + 1) * 64);
            s0v = gp[0]; s1v = gp[1]; s2v = gp[2]; s3v = gp[3];
        }

        const char* lb = (const char*)Abuf[kt & 1];
        #pragma unroll
        for (int ks = 0; ks < 2; ++ks) {
            int kk = kt * 2 + ks;
            const unsigned short* bp = bbase + (size_t)(kk * 16 + colbase8) * 512;
            bf16x8 bf[8];
            #pragma unroll
            for (int ct = 0; ct < 8; ++ct)
                bf[ct] = *(const bf16x8*)(bp + ct * 512);
            int row0 = rowbase + lo;
            int row1 = rowbase + 16 + lo;
            bf16x8 a0 = *(const bf16x8*)(lb + ((row0 * 128 + ks * 64 + hi * 16) ^ ((row0 & 7) << 4)));
            bf16x8 a1 = *(const bf16x8*)(lb + ((row1 * 128 + ks * 64 + hi * 16) ^ ((row1 & 7) << 4)));
            #pragma unroll
            for (int ct = 0; ct < 8; ++ct) {
                acc[0][ct] = __builtin_amdgcn_mfma_f32_16x16x32_bf16(a0, bf[ct], acc[0][ct], 0, 0, 0);
                acc[1][ct] = __builtin_amdgcn_mfma_f32_16x16x32_bf16(a1, bf[ct], acc[1][ct], 0, 0, 0);
            }
        }

        if (kt < 7) {
            uint4 w0 = { cvt2bf(s0v.x, s0v.y), cvt2bf(s0v.z, s0v.w),
                         cvt2bf(s1v.x, s1v.y), cvt2bf(s1v.z, s1v.w) };
            uint4 w1 = { cvt2bf(s2v.x, s2v.y), cvt2bf(s2v.z, s2v.w),
                         cvt2bf(s3v.x, s3v.y), cvt2bf(s3v.z, s3v.w) };
            char* lbw = (char*)Abuf[(kt + 1) & 1];
            *(uint4*)(lbw + wbyte0) = w0;
            *(uint4*)(lbw + wbyte1) = w1;
        }
        __syncthreads();
    }

    // ---- epilogue: energy[row] = sum_n v[n] * tanh(acc + dp[b][n]) ----
    float ps[2][4] = {{0.f, 0.f, 0.f, 0.f}, {0.f, 0.f, 0.f, 0.f}};
    #pragma unroll
    for (int ct = 0; ct < 8; ++ct) {
        int n = (colbase8 + ct) * 16 + lo;
        float dpv = dp[b * AA + n];
        float vv  = v[n];
        #pragma unroll
        for (int rt = 0; rt < 2; ++rt)
            #pragma unroll
            for (int rr = 0; rr < 4; ++rr)
                ps[rt][rr] += vv * tanh_fast(acc[rt][ct][rr] + dpv);
    }
    #pragma unroll
    for (int off = 1; off < 16; off <<= 1)
        #pragma unroll
        for (int rt = 0; rt < 2; ++rt)
            #pragma unroll
            for (int rr = 0; rr < 4; ++rr)
                ps[rt][rr] += __shfl_xor(ps[rt][rr], off);
    if (lo == 0) {
        #pragma unroll
        for (int rt = 0; rt < 2; ++rt)
            #pragma unroll
            for (int rr = 0; rr < 4; ++rr)
                part[w >> 1][rowbase + rt * 16 + 4 * hi + rr] = ps[rt][rr];
    }
    __syncthreads();
    if (tid < 64)
        energy[(size_t)b * SS + s0 + tid] = part[0][tid] + part[1][tid];
}

// K3: masked softmax over S per batch row; nan_to_num -> zeros when all masked
__global__ __launch_bounds__(1024) void k_softmax(const float* __restrict__ energy,
                                                  const int* __restrict__ mask,
                                                  float* __restrict__ attn) {
    __shared__ float se[SS];
    __shared__ float w1[16];
    __shared__ float w2[16];
    int b = blockIdx.x;
    int tid = threadIdx.x;
    int lane = tid & 63, wv = tid >> 6;
    const float* eb = energy + (size_t)b * SS;
    const int* mb = mask + (size_t)b * SS;

    float lmax = -INFINITY;
    for (int s = tid; s < SS; s += 1024) {
        float e = mb[s] ? eb[s] : -INFINITY;
        se[s] = e;
        lmax = fmaxf(lmax, e);
    }
    #pragma unroll
    for (int o = 32; o; o >>= 1) lmax = fmaxf(lmax, __shfl_down(lmax, o));
    if (!lane) w1[wv] = lmax;
    __syncthreads();
    float m = w1[0];
    #pragma unroll
    for (int i = 1; i < 16; ++i) m = fmaxf(m, w1[i]);

    float lsum = 0.f;
    for (int s = tid; s < SS; s += 1024) {
        float ev = se[s];
        float p = (ev == -INFINITY) ? 0.f : expf(ev - m);
        se[s] = p;
        lsum += p;
    }
    #pragma unroll
    for (int o = 32; o; o >>= 1) lsum += __shfl_down(lsum, o);
    if (!lane) w2[wv] = lsum;
    __syncthreads();
    float tot = 0.f;
    #pragma unroll
    for (int i = 0; i < 16; ++i) tot += w2[i];
    float inv = tot > 0.f ? 1.0f / tot : 0.f;
    float* ab = attn + (size_t)b * SS;
    for (int s = tid; s < SS; s += 1024) ab[s] = se[s] * inv;
}

// K4a: partial context
__global__ __launch_bounds__(512) void k_ctx_partial(const float* __restrict__ enc,
                                                     const float* __restrict__ attn,
                                                     float* __restrict__ partial) {
    int b = blockIdx.x, c = blockIdx.y;
    int e = threadIdx.x;
    int s0 = c * (SS / 16);
    const float* ab = attn + (size_t)b * SS + s0;
    const float* eb = enc + ((size_t)b * SS + s0) * EHH + e;
    float acc = 0.f;
    #pragma unroll 4
    for (int s = 0; s < SS / 16; ++s)
        acc = fmaf(ab[s], eb[(size_t)s * EHH], acc);
    partial[((size_t)b * 16 + c) * EHH + e] = acc;
}

// K4b: reduce 16 partials
__global__ __launch_bounds__(512) void k_ctx_reduce(const float* __restrict__ partial,
                                                    float* __restrict__ ctx) {
    int b = blockIdx.x;
    int e = threadIdx.x;
    float acc = 0.f;
    #pragma unroll
    for (int c = 0; c < 16; ++c)
        acc += partial[((size_t)b * 16 + c) * EHH + e];
    ctx[(size_t)b * EHH + e] = acc;
}

extern "C" void kernel_launch(void* const* d_in, const int* in_sizes, int n_in,
                              void* d_out, int out_size, void* d_ws, size_t ws_size,
                              hipStream_t stream) {
    const float* h    = (const float*)d_in[0];
    const float* enc  = (const float*)d_in[1];
    const int*   mask = (const int*)d_in[2];
    const float* Wd   = (const float*)d_in[3];
    const float* We   = (const float*)d_in[4];
    const float* v    = (const float*)d_in[5];

    float* out  = (float*)d_out;
    float* ctx  = out;              // (B, EH)
    float* attn = out + BB * EHH;   // (B, S)

    char* ws = (char*)d_ws;
    float* dp      = (float*)ws;                     // 32 KB
    float* energy  = (float*)(ws + 32768);           // 512 KB
    float* partial = (float*)(ws + 32768 + 524288);  // 1 MB
    // Wpack aliases partial: dead before k_ctx_partial writes; rewritten per launch
    unsigned short* Wpack = (unsigned short*)(ws + 32768 + 524288);

    k_packWe<<<AA, 512, 0, stream>>>(We, Wpack);
    k_decproj<<<BB, AA, 0, stream>>>(h, Wd, dp);
    k_energy_mfma<<<BB * SS / 64, 256, 0, stream>>>(enc, Wpack, dp, v, energy);
    k_softmax<<<BB, 1024, 0, stream>>>(energy, mask, attn);
    k_ctx_partial<<<dim3(BB, 16), 512, 0, stream>>>(enc, attn, partial);
    k_ctx_reduce<<<BB, 512, 0, stream>>>(partial, ctx);
}

// Round 5
// 145.340 us; speedup vs baseline: 4.9877x; 1.1660x over previous
//
#include <hip/hip_runtime.h>
#include <hip/hip_bf16.h>
#include <math.h>

#define BB 32
#define SS 4096
#define DHH 512
#define EHH 512
#define AA 256

typedef __attribute__((ext_vector_type(8))) short bf16x8;
typedef __attribute__((ext_vector_type(4))) float f32x4;

__device__ __forceinline__ short f2bf(float f) {
    unsigned u = __float_as_uint(f);
    u += 0x7FFFu + ((u >> 16) & 1u);   // RNE
    return (short)(u >> 16);
}

__device__ __forceinline__ unsigned cvt2bf(float a, float b) {
    __hip_bfloat162 h = __float22bfloat162_rn(float2{a, b});  // v_cvt_pk_bf16_f32
    return *(unsigned*)&h;
}

__device__ __forceinline__ float tanh_fast(float x) {
    float e = __expf(2.0f * x);
    return 1.0f - 2.0f * __builtin_amdgcn_rcpf(e + 1.0f);
}

// K0: pack We (E,A) fp32 -> fragment-major bf16:
// Wpack[((kk*16 + ctg)*64 + hi*16 + lo)*8 + j] = We[k][n],
//   k = kk*32 + hi*8 + j, n = ctg*16 + lo.
__global__ __launch_bounds__(512) void k_packWe(const float* __restrict__ We,
                                                unsigned short* __restrict__ Wpack) {
    int a = blockIdx.x;       // n
    int e = threadIdx.x;      // k
    int kk = e >> 5, hi = (e >> 3) & 3, j = e & 7;
    int ct = a >> 4, lo = a & 15;
    size_t idx = ((size_t)((kk * 16 + ct) * 64 + hi * 16 + lo)) * 8 + j;
    Wpack[idx] = (unsigned short)f2bf(We[(size_t)e * AA + a]);
}

// K1: dec_proj (tiny fp32)
__global__ __launch_bounds__(256) void k_decproj(const float* __restrict__ h,
                                                 const float* __restrict__ Wd,
                                                 float* __restrict__ dp) {
    int b = blockIdx.x;
    int a = threadIdx.x;
    float acc = 0.f;
    for (int e = 0; e < DHH; ++e)
        acc = fmaf(h[b * DHH + e], Wd[e * AA + a], acc);
    dp[b * AA + a] = acc;
}

// K2: fused energy GEMM + masked local softmax stats + partial context.
// Block = 256 thr (4 waves), tile 64 rows x 256 cols, K = 512 (8 regions of 64).
// Wave w: ALL 64 rows (rt 0..3), cols w*64..+64 (ct 0..3) -> B loads have no
// cross-wave redundancy. A staged fp32->bf16 into a PERSISTENT 64KB swizzled
// LDS tile (region per kt), pipelined. B prefetched one k-step ahead.
// Epilogue: energy, m_c/l_c, weights, and pctx[e] = sum_s w_s*enc[s][e] from LDS.
__global__ __launch_bounds__(256) void k_energy_mfma(const float* __restrict__ enc,
                                                     const unsigned short* __restrict__ Wpack,
                                                     const float* __restrict__ dp,
                                                     const float* __restrict__ v,
                                                     const int* __restrict__ mask,
                                                     float* __restrict__ energy,
                                                     float* __restrict__ pctx,
                                                     float2* __restrict__ ml) {
    __shared__ unsigned short Abuf[8][64 * 64];   // 64 KB, swizzled bf16
    __shared__ float part[4][64];
    __shared__ float wbuf[64];

    int bk = blockIdx.x;            // 2048 = 32 b * 64 chunks
    int b  = bk >> 6;
    int chunk = bk & 63;
    int s0 = chunk * 64;
    int tid = threadIdx.x;
    int l  = tid & 63;
    int w  = tid >> 6;
    int lo = l & 15;
    int hi = l >> 4;

    // staging: thread -> row r, quarter q (16 fp32 cols of the 64-col region)
    int r = tid >> 2;
    int q = tid & 3;
    const float* gbase = enc + ((size_t)b * SS + s0 + r) * EHH + q * 16;
    int wb0 = ((r * 128 + q * 32) ^ ((r & 7) << 4));
    int wb1 = ((r * 128 + q * 32 + 16) ^ ((r & 7) << 4));

    f32x4 acc[4][4];
    #pragma unroll
    for (int rt = 0; rt < 4; ++rt)
        #pragma unroll
        for (int ct = 0; ct < 4; ++ct)
            acc[rt][ct] = (f32x4){0.f, 0.f, 0.f, 0.f};

    // ---- prologue: stage region 0, prefetch B step 0 ----
    float4 s0v, s1v, s2v, s3v;
    {
        const float4* gp = (const float4*)gbase;
        s0v = gp[0]; s1v = gp[1]; s2v = gp[2]; s3v = gp[3];
        uint4 w0 = { cvt2bf(s0v.x, s0v.y), cvt2bf(s0v.z, s0v.w),
                     cvt2bf(s1v.x, s1v.y), cvt2bf(s1v.z, s1v.w) };
        uint4 w1 = { cvt2bf(s2v.x, s2v.y), cvt2bf(s2v.z, s2v.w),
                     cvt2bf(s3v.x, s3v.y), cvt2bf(s3v.z, s3v.w) };
        char* lb = (char*)Abuf[0];
        *(uint4*)(lb + wb0) = w0;
        *(uint4*)(lb + wb1) = w1;
    }
    const unsigned short* bbase = Wpack + ((size_t)(w * 4) * 64 + l) * 8;  // + step*8192 + ct*512
    bf16x8 bnext[4];
    #pragma unroll
    for (int ct = 0; ct < 4; ++ct)
        bnext[ct] = *(const bf16x8*)(bbase + ct * 512);
    __syncthreads();

    for (int kt = 0; kt < 8; ++kt) {
        if (kt < 7) {
            const float4* gp = (const float4*)(gbase + (kt + 1) * 64);
            s0v = gp[0]; s1v = gp[1]; s2v = gp[2]; s3v = gp[3];
        }
        const char* lb = (const char*)Abuf[kt];
        #pragma unroll
        for (int ks = 0; ks < 2; ++ks) {
            bf16x8 bcur[4];
            #pragma unroll
            for (int ct = 0; ct < 4; ++ct) bcur[ct] = bnext[ct];
            if (kt < 7 || ks < 1) {
                const unsigned short* bp = bbase + (size_t)(kt * 2 + ks + 1) * 8192;
                #pragma unroll
                for (int ct = 0; ct < 4; ++ct)
                    bnext[ct] = *(const bf16x8*)(bp + ct * 512);
            }
            bf16x8 afr[4];
            #pragma unroll
            for (int rt = 0; rt < 4; ++rt) {
                int row = rt * 16 + lo;
                afr[rt] = *(const bf16x8*)(lb + ((row * 128 + ks * 64 + hi * 16) ^ ((row & 7) << 4)));
            }
            #pragma unroll
            for (int rt = 0; rt < 4; ++rt)
                #pragma unroll
                for (int ct = 0; ct < 4; ++ct)
                    acc[rt][ct] = __builtin_amdgcn_mfma_f32_16x16x32_bf16(afr[rt], bcur[ct], acc[rt][ct], 0, 0, 0);
        }
        if (kt < 7) {
            uint4 w0 = { cvt2bf(s0v.x, s0v.y), cvt2bf(s0v.z, s0v.w),
                         cvt2bf(s1v.x, s1v.y), cvt2bf(s1v.z, s1v.w) };
            uint4 w1 = { cvt2bf(s2v.x, s2v.y), cvt2bf(s2v.z, s2v.w),
                         cvt2bf(s3v.x, s3v.y), cvt2bf(s3v.z, s3v.w) };
            char* lbw = (char*)Abuf[kt + 1];
            *(uint4*)(lbw + wb0) = w0;
            *(uint4*)(lbw + wb1) = w1;
        }
        __syncthreads();
    }

    // ---- energy epilogue: per-row sum of v[n]*tanh(acc + dp[n]) ----
    float ps[4][4];
    #pragma unroll
    for (int rt = 0; rt < 4; ++rt)
        #pragma unroll
        for (int rr = 0; rr < 4; ++rr) ps[rt][rr] = 0.f;
    #pragma unroll
    for (int ct = 0; ct < 4; ++ct) {
        int n = w * 64 + ct * 16 + lo;
        float dpv = dp[b * AA + n];
        float vv  = v[n];
        #pragma unroll
        for (int rt = 0; rt < 4; ++rt)
            #pragma unroll
            for (int rr = 0; rr < 4; ++rr)
                ps[rt][rr] += vv * tanh_fast(acc[rt][ct][rr] + dpv);
    }
    #pragma unroll
    for (int off = 1; off < 16; off <<= 1)
        #pragma unroll
        for (int rt = 0; rt < 4; ++rt)
            #pragma unroll
            for (int rr = 0; rr < 4; ++rr)
                ps[rt][rr] += __shfl_xor(ps[rt][rr], off);
    if (lo == 0) {
        #pragma unroll
        for (int rt = 0; rt < 4; ++rt)
            #pragma unroll
            for (int rr = 0; rr < 4; ++rr)
                part[w][rt * 16 + 4 * hi + rr] = ps[rt][rr];
    }
    __syncthreads();

    // ---- local softmax stats + weights (wave 0; lane = row s) ----
    if (w == 0) {
        float e = part[0][l] + part[1][l] + part[2][l] + part[3][l];
        energy[(size_t)b * SS + s0 + l] = e;
        int mk = mask[(size_t)b * SS + s0 + l];
        float val = mk ? e : -INFINITY;
        float m = val;
        #pragma unroll
        for (int off = 1; off < 64; off <<= 1) m = fmaxf(m, __shfl_xor(m, off));
        float wgt = (val == -INFINITY) ? 0.f : __expf(val - m);
        float lsum = wgt;
        #pragma unroll
        for (int off = 1; off < 64; off <<= 1) lsum += __shfl_xor(lsum, off);
        wbuf[l] = wgt;
        if (l == 0) ml[(size_t)b * 64 + chunk] = float2{m, lsum};
    }
    __syncthreads();

    // ---- partial context: pctx[e] = sum_s wgt[s] * enc_bf16[s][e] from LDS ----
    {
        int e0 = tid * 2;
        int reg = e0 >> 6;
        int c   = e0 & 63;
        const char* lb = (const char*)Abuf[reg];
        float a0 = 0.f, a1 = 0.f;
        #pragma unroll 8
        for (int s = 0; s < 64; ++s) {
            float wv_ = wbuf[s];
            unsigned u = *(const unsigned*)(lb + ((s * 128 + c * 2) ^ ((s & 7) << 4)));
            float x0 = __uint_as_float(u << 16);
            float x1 = __uint_as_float(u & 0xFFFF0000u);
            a0 = fmaf(wv_, x0, a0);
            a1 = fmaf(wv_, x1, a1);
        }
        *(float2*)&pctx[((size_t)(b * 64 + chunk)) * 512 + e0] = float2{a0, a1};
    }
}

// K3: masked softmax over S per batch row (attn output); nan_to_num -> zeros
__global__ __launch_bounds__(1024) void k_softmax(const float* __restrict__ energy,
                                                  const int* __restrict__ mask,
                                                  float* __restrict__ attn) {
    __shared__ float se[SS];
    __shared__ float w1[16];
    __shared__ float w2[16];
    int b = blockIdx.x;
    int tid = threadIdx.x;
    int lane = tid & 63, wv = tid >> 6;
    const float* eb = energy + (size_t)b * SS;
    const int* mb = mask + (size_t)b * SS;

    float lmax = -INFINITY;
    for (int s = tid; s < SS; s += 1024) {
        float e = mb[s] ? eb[s] : -INFINITY;
        se[s] = e;
        lmax = fmaxf(lmax, e);
    }
    #pragma unroll
    for (int o = 32; o; o >>= 1) lmax = fmaxf(lmax, __shfl_down(lmax, o));
    if (!lane) w1[wv] = lmax;
    __syncthreads();
    float m = w1[0];
    #pragma unroll
    for (int i = 1; i < 16; ++i) m = fmaxf(m, w1[i]);

    float lsum = 0.f;
    for (int s = tid; s < SS; s += 1024) {
        float ev = se[s];
        float p = (ev == -INFINITY) ? 0.f : expf(ev - m);
        se[s] = p;
        lsum += p;
    }
    #pragma unroll
    for (int o = 32; o; o >>= 1) lsum += __shfl_down(lsum, o);
    if (!lane) w2[wv] = lsum;
    __syncthreads();
    float tot = 0.f;
    #pragma unroll
    for (int i = 0; i < 16; ++i) tot += w2[i];
    float inv = tot > 0.f ? 1.0f / tot : 0.f;
    float* ab = attn + (size_t)b * SS;
    for (int s = tid; s < SS; s += 1024) ab[s] = se[s] * inv;
}

// K4: final context = rescaled sum of 64 chunk partials per batch
__global__ __launch_bounds__(512) void k_ctx_final(const float* __restrict__ pctx,
                                                   const float2* __restrict__ ml,
                                                   float* __restrict__ ctx) {
    __shared__ float scal[64];
    __shared__ float invZ;
    int b = blockIdx.x;
    int tid = threadIdx.x;
    if (tid < 64) {
        float2 p = ml[(size_t)b * 64 + tid];
        float m = p.x;
        #pragma unroll
        for (int off = 1; off < 64; off <<= 1) m = fmaxf(m, __shfl_xor(m, off));
        float sc = (p.x == -INFINITY) ? 0.f : __expf(p.x - m);
        scal[tid] = sc;
        float z = sc * p.y;
        #pragma unroll
        for (int off = 1; off < 64; off <<= 1) z += __shfl_xor(z, off);
        if (tid == 0) invZ = (z > 0.f) ? 1.0f / z : 0.f;
    }
    __syncthreads();
    float acc = 0.f;
    #pragma unroll 8
    for (int c = 0; c < 64; ++c)
        acc = fmaf(scal[c], pctx[((size_t)(b * 64 + c)) * 512 + tid], acc);
    ctx[(size_t)b * EHH + tid] = acc * invZ;
}

extern "C" void kernel_launch(void* const* d_in, const int* in_sizes, int n_in,
                              void* d_out, int out_size, void* d_ws, size_t ws_size,
                              hipStream_t stream) {
    const float* h    = (const float*)d_in[0];
    const float* enc  = (const float*)d_in[1];
    const int*   mask = (const int*)d_in[2];
    const float* Wd   = (const float*)d_in[3];
    const float* We   = (const float*)d_in[4];
    const float* v    = (const float*)d_in[5];

    float* out  = (float*)d_out;
    float* ctx  = out;              // (B, EH)
    float* attn = out + BB * EHH;   // (B, S)

    char* ws = (char*)d_ws;
    float*          dp     = (float*)ws;                          // 32 KB
    float*          energy = (float*)(ws + (32 << 10));           // 512 KB
    unsigned short* Wpack  = (unsigned short*)(ws + (576 << 10)); // 256 KB
    float*          pctx   = (float*)(ws + (1 << 20));            // 4 MB
    float2*         ml     = (float2*)(ws + (5 << 20));           // 16 KB

    k_packWe<<<AA, 512, 0, stream>>>(We, Wpack);
    k_decproj<<<BB, AA, 0, stream>>>(h, Wd, dp);
    k_energy_mfma<<<BB * SS / 64, 256, 0, stream>>>(enc, Wpack, dp, v, mask,
                                                    energy, pctx, ml);
    k_softmax<<<BB, 1024, 0, stream>>>(energy, mask, attn);
    k_ctx_final<<<BB, 512, 0, stream>>>(pctx, ml, ctx);
}

// Round 6
// 125.110 us; speedup vs baseline: 5.7942x; 1.1617x over previous
//
#include <hip/hip_runtime.h>
#include <hip/hip_bf16.h>
#include <math.h>

#define BB 32
#define SS 4096
#define DHH 512
#define EHH 512
#define AA 256

typedef __attribute__((ext_vector_type(8))) short bf16x8;
typedef __attribute__((ext_vector_type(4))) float f32x4;

__device__ __forceinline__ short f2bf(float f) {
    unsigned u = __float_as_uint(f);
    u += 0x7FFFu + ((u >> 16) & 1u);   // RNE
    return (short)(u >> 16);
}

__device__ __forceinline__ unsigned cvt2bf(float a, float b) {
    __hip_bfloat162 h = __float22bfloat162_rn(float2{a, b});  // v_cvt_pk_bf16_f32
    return *(unsigned*)&h;
}

__device__ __forceinline__ float tanh_fast(float x) {
    float e = __expf(2.0f * x);
    return 1.0f - 2.0f * __builtin_amdgcn_rcpf(e + 1.0f);
}

// K0: pack We (E,A) fp32 -> fragment-major bf16:
// Wpack[((kk*16 + ct)*64 + hi*16 + lo)*8 + j] = We[k][n], k = kk*32+hi*8+j, n = ct*16+lo
__global__ __launch_bounds__(512) void k_packWe(const float* __restrict__ We,
                                                unsigned short* __restrict__ Wpack) {
    int a = blockIdx.x;
    int e = threadIdx.x;
    int kk = e >> 5, hi = (e >> 3) & 3, j = e & 7;
    int ct = a >> 4, lo = a & 15;
    size_t idx = ((size_t)((kk * 16 + ct) * 64 + hi * 16 + lo)) * 8 + j;
    Wpack[idx] = (unsigned short)f2bf(We[(size_t)e * AA + a]);
}

// K1: dec_proj (tiny fp32)
__global__ __launch_bounds__(256) void k_decproj(const float* __restrict__ h,
                                                 const float* __restrict__ Wd,
                                                 float* __restrict__ dp) {
    int b = blockIdx.x;
    int a = threadIdx.x;
    float acc = 0.f;
    for (int e = 0; e < DHH; ++e)
        acc = fmaf(h[b * DHH + e], Wd[e * AA + a], acc);
    dp[b * AA + a] = acc;
}

// K2: fused energy GEMM + local softmax stats + partial context.
// Chunk = 32 rows (128 chunks/batch). Block = 256 thr (4 waves).
// Wave w: all 32 rows (rt 0..1), cols w*64..+64 (ct 0..3). K = 512 (8 regions of 64).
// LDS 33KB -> 4 blocks/CU (4 waves/SIMD) for 2x the latency-hiding of R5.
__global__ __launch_bounds__(256, 4) void k_energy_mfma(const float* __restrict__ enc,
                                                        const unsigned short* __restrict__ Wpack,
                                                        const float* __restrict__ dp,
                                                        const float* __restrict__ v,
                                                        const int* __restrict__ mask,
                                                        float* __restrict__ energy,
                                                        float* __restrict__ pctx,
                                                        float2* __restrict__ ml) {
    __shared__ unsigned short Abuf[8][32 * 64];   // 32 KB, swizzled bf16
    __shared__ float part[4][32];
    __shared__ float wbuf[32];

    int bk = blockIdx.x;            // 4096 = 32 b * 128 chunks
    int b  = bk >> 7;
    int chunk = bk & 127;
    int s0 = chunk * 32;
    int tid = threadIdx.x;
    int l  = tid & 63;
    int w  = tid >> 6;
    int lo = l & 15;
    int hi = l >> 4;

    // staging: thread -> row r (0..31), 8-float group q (0..7)
    int r = tid >> 3;
    int q = tid & 7;
    const float* gbase = enc + ((size_t)b * SS + s0 + r) * EHH + q * 8;
    int wb0 = ((r * 128 + q * 16) ^ ((r & 7) << 4));

    f32x4 acc[2][4];
    #pragma unroll
    for (int rt = 0; rt < 2; ++rt)
        #pragma unroll
        for (int ct = 0; ct < 4; ++ct)
            acc[rt][ct] = (f32x4){0.f, 0.f, 0.f, 0.f};

    // ---- prologue: stage region 0, prefetch B step 0 ----
    float4 sv0, sv1;
    {
        const float4* gp = (const float4*)gbase;
        sv0 = gp[0]; sv1 = gp[1];
        uint4 w0 = { cvt2bf(sv0.x, sv0.y), cvt2bf(sv0.z, sv0.w),
                     cvt2bf(sv1.x, sv1.y), cvt2bf(sv1.z, sv1.w) };
        *(uint4*)((char*)Abuf[0] + wb0) = w0;
    }
    const unsigned short* bbase = Wpack + ((size_t)(w * 4) * 64 + l) * 8;  // + kk*8192 + ct*512
    bf16x8 bnext[4];
    #pragma unroll
    for (int ct = 0; ct < 4; ++ct)
        bnext[ct] = *(const bf16x8*)(bbase + ct * 512);
    __syncthreads();

    for (int kt = 0; kt < 8; ++kt) {
        if (kt < 7) {
            const float4* gp = (const float4*)(gbase + (kt + 1) * 64);
            sv0 = gp[0]; sv1 = gp[1];
        }
        const char* lb = (const char*)Abuf[kt];
        #pragma unroll
        for (int ks = 0; ks < 2; ++ks) {
            bf16x8 bcur[4];
            #pragma unroll
            for (int ct = 0; ct < 4; ++ct) bcur[ct] = bnext[ct];
            if (kt * 2 + ks < 15) {
                const unsigned short* bp = bbase + (size_t)(kt * 2 + ks + 1) * 8192;
                #pragma unroll
                for (int ct = 0; ct < 4; ++ct)
                    bnext[ct] = *(const bf16x8*)(bp + ct * 512);
            }
            bf16x8 afr[2];
            #pragma unroll
            for (int rt = 0; rt < 2; ++rt) {
                int row = rt * 16 + lo;
                afr[rt] = *(const bf16x8*)(lb + ((row * 128 + ks * 64 + hi * 16) ^ ((row & 7) << 4)));
            }
            #pragma unroll
            for (int rt = 0; rt < 2; ++rt)
                #pragma unroll
                for (int ct = 0; ct < 4; ++ct)
                    acc[rt][ct] = __builtin_amdgcn_mfma_f32_16x16x32_bf16(afr[rt], bcur[ct], acc[rt][ct], 0, 0, 0);
        }
        if (kt < 7) {
            uint4 w0 = { cvt2bf(sv0.x, sv0.y), cvt2bf(sv0.z, sv0.w),
                         cvt2bf(sv1.x, sv1.y), cvt2bf(sv1.z, sv1.w) };
            *(uint4*)((char*)Abuf[kt + 1] + wb0) = w0;
        }
        __syncthreads();
    }

    // ---- energy epilogue: per-row sum of v[n]*tanh(acc + dp[n]) ----
    float ps[2][4];
    #pragma unroll
    for (int rt = 0; rt < 2; ++rt)
        #pragma unroll
        for (int rr = 0; rr < 4; ++rr) ps[rt][rr] = 0.f;
    #pragma unroll
    for (int ct = 0; ct < 4; ++ct) {
        int n = w * 64 + ct * 16 + lo;
        float dpv = dp[b * AA + n];
        float vv  = v[n];
        #pragma unroll
        for (int rt = 0; rt < 2; ++rt)
            #pragma unroll
            for (int rr = 0; rr < 4; ++rr)
                ps[rt][rr] += vv * tanh_fast(acc[rt][ct][rr] + dpv);
    }
    #pragma unroll
    for (int off = 1; off < 16; off <<= 1)
        #pragma unroll
        for (int rt = 0; rt < 2; ++rt)
            #pragma unroll
            for (int rr = 0; rr < 4; ++rr)
                ps[rt][rr] += __shfl_xor(ps[rt][rr], off);
    if (lo == 0) {
        #pragma unroll
        for (int rt = 0; rt < 2; ++rt)
            #pragma unroll
            for (int rr = 0; rr < 4; ++rr)
                part[w][rt * 16 + 4 * hi + rr] = ps[rt][rr];
    }
    __syncthreads();

    // ---- local softmax stats + weights (wave 0, lanes 0..31; lane = row s) ----
    if (w == 0 && l < 32) {
        float e = part[0][l] + part[1][l] + part[2][l] + part[3][l];
        energy[(size_t)b * SS + s0 + l] = e;
        int mk = mask[(size_t)b * SS + s0 + l];
        float val = mk ? e : -INFINITY;
        float m = val;
        #pragma unroll
        for (int off = 1; off < 32; off <<= 1) m = fmaxf(m, __shfl_xor(m, off));
        float wgt = (val == -INFINITY) ? 0.f : __expf(val - m);
        float lsum = wgt;
        #pragma unroll
        for (int off = 1; off < 32; off <<= 1) lsum += __shfl_xor(lsum, off);
        wbuf[l] = wgt;
        if (l == 0) ml[(size_t)b * 128 + chunk] = float2{m, lsum};
    }
    __syncthreads();

    // ---- partial context: pctx[e] = sum_s wgt[s] * enc_bf16[s][e] from LDS ----
    {
        int e0 = tid * 2;
        int reg = e0 >> 6;
        int c   = e0 & 63;
        const char* lb = (const char*)Abuf[reg];
        float a0 = 0.f, a1 = 0.f;
        #pragma unroll 8
        for (int s = 0; s < 32; ++s) {
            float wv_ = wbuf[s];
            unsigned u = *(const unsigned*)(lb + ((s * 128 + c * 2) ^ ((s & 7) << 4)));
            float x0 = __uint_as_float(u << 16);
            float x1 = __uint_as_float(u & 0xFFFF0000u);
            a0 = fmaf(wv_, x0, a0);
            a1 = fmaf(wv_, x1, a1);
        }
        *(float2*)&pctx[((size_t)(b * 128 + chunk)) * 512 + e0] = float2{a0, a1};
    }
}

// K3: one-pass masked softmax using per-chunk (m,l) stats. Grid (16 slices, B).
__global__ __launch_bounds__(256) void k_softmax(const float* __restrict__ energy,
                                                 const int* __restrict__ mask,
                                                 const float2* __restrict__ ml,
                                                 float* __restrict__ attn) {
    __shared__ float wm[4], wz[4];
    int b = blockIdx.y;
    int tid = threadIdx.x;
    int l = tid & 63, w = tid >> 6;

    float2 p = float2{-INFINITY, 0.f};
    if (tid < 128) p = ml[(size_t)b * 128 + tid];
    float m = p.x;
    #pragma unroll
    for (int off = 1; off < 64; off <<= 1) m = fmaxf(m, __shfl_xor(m, off));
    if (!l) wm[w] = m;
    __syncthreads();
    float M = fmaxf(fmaxf(wm[0], wm[1]), fmaxf(wm[2], wm[3]));
    float z = (p.x == -INFINITY) ? 0.f : __expf(p.x - M) * p.y;
    #pragma unroll
    for (int off = 1; off < 64; off <<= 1) z += __shfl_xor(z, off);
    if (!l) wz[w] = z;
    __syncthreads();
    float Z = wz[0] + wz[1] + wz[2] + wz[3];
    float invZ = (Z > 0.f) ? 1.0f / Z : 0.f;

    int s = blockIdx.x * 256 + tid;
    float e = energy[(size_t)b * SS + s];
    int mk = mask[(size_t)b * SS + s];
    attn[(size_t)b * SS + s] = mk ? __expf(e - M) * invZ : 0.f;
}

// K4: final context = rescaled sum of 128 chunk partials per batch
__global__ __launch_bounds__(512) void k_ctx_final(const float* __restrict__ pctx,
                                                   const float2* __restrict__ ml,
                                                   float* __restrict__ ctx) {
    __shared__ float scal[128];
    __shared__ float wm[8], wz[8];
    int b = blockIdx.x;
    int tid = threadIdx.x;
    int l = tid & 63, w = tid >> 6;

    float2 p = float2{-INFINITY, 0.f};
    if (tid < 128) p = ml[(size_t)b * 128 + tid];
    float m = p.x;
    #pragma unroll
    for (int off = 1; off < 64; off <<= 1) m = fmaxf(m, __shfl_xor(m, off));
    if (!l) wm[w] = m;
    __syncthreads();
    float M = wm[0];
    #pragma unroll
    for (int i = 1; i < 8; ++i) M = fmaxf(M, wm[i]);
    float sc = (p.x == -INFINITY) ? 0.f : __expf(p.x - M);
    if (tid < 128) scal[tid] = sc;
    float z = sc * p.y;
    #pragma unroll
    for (int off = 1; off < 64; off <<= 1) z += __shfl_xor(z, off);
    if (!l) wz[w] = z;
    __syncthreads();
    float Z = 0.f;
    #pragma unroll
    for (int i = 0; i < 8; ++i) Z += wz[i];
    float invZ = (Z > 0.f) ? 1.0f / Z : 0.f;

    float acc = 0.f;
    #pragma unroll 8
    for (int c = 0; c < 128; ++c)
        acc = fmaf(scal[c], pctx[((size_t)(b * 128 + c)) * 512 + tid], acc);
    ctx[(size_t)b * EHH + tid] = acc * invZ;
}

extern "C" void kernel_launch(void* const* d_in, const int* in_sizes, int n_in,
                              void* d_out, int out_size, void* d_ws, size_t ws_size,
                              hipStream_t stream) {
    const float* h    = (const float*)d_in[0];
    const float* enc  = (const float*)d_in[1];
    const int*   mask = (const int*)d_in[2];
    const float* Wd   = (const float*)d_in[3];
    const float* We   = (const float*)d_in[4];
    const float* v    = (const float*)d_in[5];

    float* out  = (float*)d_out;
    float* ctx  = out;              // (B, EH)
    float* attn = out + BB * EHH;   // (B, S)

    char* ws = (char*)d_ws;
    float*          dp     = (float*)ws;                          // 32 KB
    float*          energy = (float*)(ws + (32 << 10));           // 512 KB
    unsigned short* Wpack  = (unsigned short*)(ws + (576 << 10)); // 256 KB
    float*          pctx   = (float*)(ws + (1 << 20));            // 8 MB
    float2*         ml     = (float2*)(ws + (9 << 20));           // 32 KB

    k_packWe<<<AA, 512, 0, stream>>>(We, Wpack);
    k_decproj<<<BB, AA, 0, stream>>>(h, Wd, dp);
    k_energy_mfma<<<BB * SS / 32, 256, 0, stream>>>(enc, Wpack, dp, v, mask,
                                                    energy, pctx, ml);
    k_softmax<<<dim3(16, BB), 256, 0, stream>>>(energy, mask, ml, attn);
    k_ctx_final<<<BB, 512, 0, stream>>>(pctx, ml, ctx);
}

// Round 7
// 122.193 us; speedup vs baseline: 5.9325x; 1.0239x over previous
//
#include <hip/hip_runtime.h>
#include <hip/hip_bf16.h>
#include <math.h>

#define BB 32
#define SS 4096
#define DHH 512
#define EHH 512
#define AA 256

typedef __attribute__((ext_vector_type(8))) short bf16x8;
typedef __attribute__((ext_vector_type(4))) float f32x4;

__device__ __forceinline__ short f2bf(float f) {
    unsigned u = __float_as_uint(f);
    u += 0x7FFFu + ((u >> 16) & 1u);   // RNE
    return (short)(u >> 16);
}

__device__ __forceinline__ unsigned cvt2bf(float a, float b) {
    __hip_bfloat162 h = __float22bfloat162_rn(float2{a, b});  // v_cvt_pk_bf16_f32
    return *(unsigned*)&h;
}

__device__ __forceinline__ float tanh_fast(float x) {
    float e = __expf(2.0f * x);
    return 1.0f - 2.0f * __builtin_amdgcn_rcpf(e + 1.0f);
}

// K0: pack We (E,A) fp32 -> fragment-major bf16:
// Wpack[((kk*16 + ct)*64 + hi*16 + lo)*8 + j] = We[k][n], k = kk*32+hi*8+j, n = ct*16+lo
__global__ __launch_bounds__(512) void k_packWe(const float* __restrict__ We,
                                                unsigned short* __restrict__ Wpack) {
    int a = blockIdx.x;
    int e = threadIdx.x;
    int kk = e >> 5, hi = (e >> 3) & 3, j = e & 7;
    int ct = a >> 4, lo = a & 15;
    size_t idx = ((size_t)((kk * 16 + ct) * 64 + hi * 16 + lo)) * 8 + j;
    Wpack[idx] = (unsigned short)f2bf(We[(size_t)e * AA + a]);
}

// K1: dec_proj (tiny fp32)
__global__ __launch_bounds__(256) void k_decproj(const float* __restrict__ h,
                                                 const float* __restrict__ Wd,
                                                 float* __restrict__ dp) {
    int b = blockIdx.x;
    int a = threadIdx.x;
    float acc = 0.f;
    for (int e = 0; e < DHH; ++e)
        acc = fmaf(h[b * DHH + e], Wd[e * AA + a], acc);
    dp[b * AA + a] = acc;
}

// K2: fused energy GEMM + local softmax stats + partial context.
// Chunk = 32 rows. Block = 256 thr (4 waves), wave w: all 32 rows, cols w*64..+64.
// A-stage loads issued 3 kt ahead of their LDS write (in-flight ~700cy ~ HBM lat);
// B prefetched 2 ks-steps ahead (~300cy > L2 lat). kt loop fully unrolled so all
// pipeline registers have static indices.
__global__ __launch_bounds__(256, 4) void k_energy_mfma(const float* __restrict__ enc,
                                                        const unsigned short* __restrict__ Wpack,
                                                        const float* __restrict__ dp,
                                                        const float* __restrict__ v,
                                                        const int* __restrict__ mask,
                                                        float* __restrict__ energy,
                                                        float* __restrict__ pctx,
                                                        float2* __restrict__ ml) {
    __shared__ unsigned short Abuf[8][32 * 64];   // 32 KB, swizzled bf16
    __shared__ float part[4][32];
    __shared__ float wbuf[32];

    int bk = blockIdx.x;            // 4096 = 32 b * 128 chunks
    int b  = bk >> 7;
    int chunk = bk & 127;
    int s0 = chunk * 32;
    int tid = threadIdx.x;
    int l  = tid & 63;
    int w  = tid >> 6;
    int lo = l & 15;
    int hi = l >> 4;

    // staging: thread -> row r (0..31), 8-float group q (0..7)
    int r = tid >> 3;
    int q = tid & 7;
    const float* gbase = enc + ((size_t)b * SS + s0 + r) * EHH + q * 8;
    int wb0 = ((r * 128 + q * 16) ^ ((r & 7) << 4));

    f32x4 acc[2][4];
    #pragma unroll
    for (int rt = 0; rt < 2; ++rt)
        #pragma unroll
        for (int ct = 0; ct < 4; ++ct)
            acc[rt][ct] = (f32x4){0.f, 0.f, 0.f, 0.f};

    // ---- prologue: issue A sets 0..2, write region 0, prefetch B kk=0,1 ----
    float4 sva[8], svb[8];
    {
        const float4* gp = (const float4*)gbase;
        sva[0] = gp[0]; svb[0] = gp[1];
    }
    {
        const float4* gp = (const float4*)(gbase + 64);
        sva[1] = gp[0]; svb[1] = gp[1];
    }
    {
        const float4* gp = (const float4*)(gbase + 128);
        sva[2] = gp[0]; svb[2] = gp[1];
    }
    {
        uint4 w0 = { cvt2bf(sva[0].x, sva[0].y), cvt2bf(sva[0].z, sva[0].w),
                     cvt2bf(svb[0].x, svb[0].y), cvt2bf(svb[0].z, svb[0].w) };
        *(uint4*)((char*)Abuf[0] + wb0) = w0;
    }
    const unsigned short* bbase = Wpack + ((size_t)(w * 4) * 64 + l) * 8;  // + kk*8192 + ct*512
    bf16x8 bn0[4], bn1[4];
    #pragma unroll
    for (int ct = 0; ct < 4; ++ct) bn0[ct] = *(const bf16x8*)(bbase + ct * 512);
    #pragma unroll
    for (int ct = 0; ct < 4; ++ct) bn1[ct] = *(const bf16x8*)(bbase + 8192 + ct * 512);
    __syncthreads();

    #pragma unroll
    for (int kt = 0; kt < 8; ++kt) {
        // issue A-stage loads 3 kt ahead
        if (kt + 3 < 8) {
            const float4* gp = (const float4*)(gbase + (kt + 3) * 64);
            sva[kt + 3] = gp[0]; svb[kt + 3] = gp[1];
        }
        const char* lb = (const char*)Abuf[kt];
        #pragma unroll
        for (int ks = 0; ks < 2; ++ks) {
            int g = kt * 2 + ks;
            bf16x8 bcur[4];
            #pragma unroll
            for (int ct = 0; ct < 4; ++ct) { bcur[ct] = bn0[ct]; bn0[ct] = bn1[ct]; }
            if (g + 2 < 16) {
                const unsigned short* bp = bbase + (size_t)(g + 2) * 8192;
                #pragma unroll
                for (int ct = 0; ct < 4; ++ct)
                    bn1[ct] = *(const bf16x8*)(bp + ct * 512);
            }
            bf16x8 afr[2];
            #pragma unroll
            for (int rt = 0; rt < 2; ++rt) {
                int row = rt * 16 + lo;
                afr[rt] = *(const bf16x8*)(lb + ((row * 128 + ks * 64 + hi * 16) ^ ((row & 7) << 4)));
            }
            #pragma unroll
            for (int rt = 0; rt < 2; ++rt)
                #pragma unroll
                for (int ct = 0; ct < 4; ++ct)
                    acc[rt][ct] = __builtin_amdgcn_mfma_f32_16x16x32_bf16(afr[rt], bcur[ct], acc[rt][ct], 0, 0, 0);
        }
        // write next region (its loads were issued 2-3 kt ago -> vmcnt wait ~0)
        if (kt < 7) {
            uint4 w0 = { cvt2bf(sva[kt + 1].x, sva[kt + 1].y), cvt2bf(sva[kt + 1].z, sva[kt + 1].w),
                         cvt2bf(svb[kt + 1].x, svb[kt + 1].y), cvt2bf(svb[kt + 1].z, svb[kt + 1].w) };
            *(uint4*)((char*)Abuf[kt + 1] + wb0) = w0;
        }
        __syncthreads();
    }

    // ---- energy epilogue: per-row sum of v[n]*tanh(acc + dp[n]) ----
    float ps[2][4];
    #pragma unroll
    for (int rt = 0; rt < 2; ++rt)
        #pragma unroll
        for (int rr = 0; rr < 4; ++rr) ps[rt][rr] = 0.f;
    #pragma unroll
    for (int ct = 0; ct < 4; ++ct) {
        int n = w * 64 + ct * 16 + lo;
        float dpv = dp[b * AA + n];
        float vv  = v[n];
        #pragma unroll
        for (int rt = 0; rt < 2; ++rt)
            #pragma unroll
            for (int rr = 0; rr < 4; ++rr)
                ps[rt][rr] += vv * tanh_fast(acc[rt][ct][rr] + dpv);
    }
    #pragma unroll
    for (int off = 1; off < 16; off <<= 1)
        #pragma unroll
        for (int rt = 0; rt < 2; ++rt)
            #pragma unroll
            for (int rr = 0; rr < 4; ++rr)
                ps[rt][rr] += __shfl_xor(ps[rt][rr], off);
    if (lo == 0) {
        #pragma unroll
        for (int rt = 0; rt < 2; ++rt)
            #pragma unroll
            for (int rr = 0; rr < 4; ++rr)
                part[w][rt * 16 + 4 * hi + rr] = ps[rt][rr];
    }
    __syncthreads();

    // ---- local softmax stats + weights (wave 0, lanes 0..31; lane = row s) ----
    if (w == 0 && l < 32) {
        float e = part[0][l] + part[1][l] + part[2][l] + part[3][l];
        energy[(size_t)b * SS + s0 + l] = e;
        int mk = mask[(size_t)b * SS + s0 + l];
        float val = mk ? e : -INFINITY;
        float m = val;
        #pragma unroll
        for (int off = 1; off < 32; off <<= 1) m = fmaxf(m, __shfl_xor(m, off));
        float wgt = (val == -INFINITY) ? 0.f : __expf(val - m);
        float lsum = wgt;
        #pragma unroll
        for (int off = 1; off < 32; off <<= 1) lsum += __shfl_xor(lsum, off);
        wbuf[l] = wgt;
        if (l == 0) ml[(size_t)b * 128 + chunk] = float2{m, lsum};
    }
    __syncthreads();

    // ---- partial context: pctx[e] = sum_s wgt[s] * enc_bf16[s][e] from LDS ----
    {
        int e0 = tid * 2;
        int reg = e0 >> 6;
        int c   = e0 & 63;
        const char* lb = (const char*)Abuf[reg];
        float a0 = 0.f, a1 = 0.f;
        #pragma unroll 8
        for (int s = 0; s < 32; ++s) {
            float wv_ = wbuf[s];
            unsigned u = *(const unsigned*)(lb + ((s * 128 + c * 2) ^ ((s & 7) << 4)));
            float x0 = __uint_as_float(u << 16);
            float x1 = __uint_as_float(u & 0xFFFF0000u);
            a0 = fmaf(wv_, x0, a0);
            a1 = fmaf(wv_, x1, a1);
        }
        *(float2*)&pctx[((size_t)(b * 128 + chunk)) * 512 + e0] = float2{a0, a1};
    }
}

// K3: one-pass masked softmax using per-chunk (m,l) stats. Grid (16 slices, B).
__global__ __launch_bounds__(256) void k_softmax(const float* __restrict__ energy,
                                                 const int* __restrict__ mask,
                                                 const float2* __restrict__ ml,
                                                 float* __restrict__ attn) {
    __shared__ float wm[4], wz[4];
    int b = blockIdx.y;
    int tid = threadIdx.x;
    int l = tid & 63, w = tid >> 6;

    float2 p = float2{-INFINITY, 0.f};
    if (tid < 128) p = ml[(size_t)b * 128 + tid];
    float m = p.x;
    #pragma unroll
    for (int off = 1; off < 64; off <<= 1) m = fmaxf(m, __shfl_xor(m, off));
    if (!l) wm[w] = m;
    __syncthreads();
    float M = fmaxf(fmaxf(wm[0], wm[1]), fmaxf(wm[2], wm[3]));
    float z = (p.x == -INFINITY) ? 0.f : __expf(p.x - M) * p.y;
    #pragma unroll
    for (int off = 1; off < 64; off <<= 1) z += __shfl_xor(z, off);
    if (!l) wz[w] = z;
    __syncthreads();
    float Z = wz[0] + wz[1] + wz[2] + wz[3];
    float invZ = (Z > 0.f) ? 1.0f / Z : 0.f;

    int s = blockIdx.x * 256 + tid;
    float e = energy[(size_t)b * SS + s];
    int mk = mask[(size_t)b * SS + s];
    attn[(size_t)b * SS + s] = mk ? __expf(e - M) * invZ : 0.f;
}

// K4: final context = rescaled sum of 128 chunk partials per batch
__global__ __launch_bounds__(512) void k_ctx_final(const float* __restrict__ pctx,
                                                   const float2* __restrict__ ml,
                                                   float* __restrict__ ctx) {
    __shared__ float scal[128];
    __shared__ float wm[8], wz[8];
    int b = blockIdx.x;
    int tid = threadIdx.x;
    int l = tid & 63, w = tid >> 6;

    float2 p = float2{-INFINITY, 0.f};
    if (tid < 128) p = ml[(size_t)b * 128 + tid];
    float m = p.x;
    #pragma unroll
    for (int off = 1; off < 64; off <<= 1) m = fmaxf(m, __shfl_xor(m, off));
    if (!l) wm[w] = m;
    __syncthreads();
    float M = wm[0];
    #pragma unroll
    for (int i = 1; i < 8; ++i) M = fmaxf(M, wm[i]);
    float sc = (p.x == -INFINITY) ? 0.f : __expf(p.x - M);
    if (tid < 128) scal[tid] = sc;
    float z = sc * p.y;
    #pragma unroll
    for (int off = 1; off < 64; off <<= 1) z += __shfl_xor(z, off);
    if (!l) wz[w] = z;
    __syncthreads();
    float Z = 0.f;
    #pragma unroll
    for (int i = 0; i < 8; ++i) Z += wz[i];
    float invZ = (Z > 0.f) ? 1.0f / Z : 0.f;

    float acc = 0.f;
    #pragma unroll 8
    for (int c = 0; c < 128; ++c)
        acc = fmaf(scal[c], pctx[((size_t)(b * 128 + c)) * 512 + tid], acc);
    ctx[(size_t)b * EHH + tid] = acc * invZ;
}

extern "C" void kernel_launch(void* const* d_in, const int* in_sizes, int n_in,
                              void* d_out, int out_size, void* d_ws, size_t ws_size,
                              hipStream_t stream) {
    const float* h    = (const float*)d_in[0];
    const float* enc  = (const float*)d_in[1];
    const int*   mask = (const int*)d_in[2];
    const float* Wd   = (const float*)d_in[3];
    const float* We   = (const float*)d_in[4];
    const float* v    = (const float*)d_in[5];

    float* out  = (float*)d_out;
    float* ctx  = out;              // (B, EH)
    float* attn = out + BB * EHH;   // (B, S)

    char* ws = (char*)d_ws;
    float*          dp     = (float*)ws;                          // 32 KB
    float*          energy = (float*)(ws + (32 << 10));           // 512 KB
    unsigned short* Wpack  = (unsigned short*)(ws + (576 << 10)); // 256 KB
    float*          pctx   = (float*)(ws + (1 << 20));            // 8 MB
    float2*         ml     = (float2*)(ws + (9 << 20));           // 32 KB

    k_packWe<<<AA, 512, 0, stream>>>(We, Wpack);
    k_decproj<<<BB, AA, 0, stream>>>(h, Wd, dp);
    k_energy_mfma<<<BB * SS / 32, 256, 0, stream>>>(enc, Wpack, dp, v, mask,
                                                    energy, pctx, ml);
    k_softmax<<<dim3(16, BB), 256, 0, stream>>>(energy, mask, ml, attn);
    k_ctx_final<<<BB, 512, 0, stream>>>(pctx, ml, ctx);
}

// Round 8
// 120.612 us; speedup vs baseline: 6.0103x; 1.0131x over previous
//
#include <hip/hip_runtime.h>
#include <hip/hip_bf16.h>
#include <math.h>

#define BB 32
#define SS 4096
#define DHH 512
#define EHH 512
#define AA 256

typedef __attribute__((ext_vector_type(8))) short bf16x8;
typedef __attribute__((ext_vector_type(4))) float f32x4;

__device__ __forceinline__ short f2bf(float f) {
    unsigned u = __float_as_uint(f);
    u += 0x7FFFu + ((u >> 16) & 1u);   // RNE
    return (short)(u >> 16);
}

__device__ __forceinline__ unsigned cvt2bf(float a, float b) {
    __hip_bfloat162 h = __float22bfloat162_rn(float2{a, b});  // v_cvt_pk_bf16_f32
    return *(unsigned*)&h;
}

__device__ __forceinline__ float tanh_fast(float x) {
    float e = __expf(2.0f * x);
    return 1.0f - 2.0f * __builtin_amdgcn_rcpf(e + 1.0f);
}

// K0: pack We (E,A) fp32 -> fragment-major bf16:
// Wpack[((kk*16 + ct)*64 + hi*16 + lo)*8 + j] = We[k][n], k = kk*32+hi*8+j, n = ct*16+lo
__global__ __launch_bounds__(512) void k_packWe(const float* __restrict__ We,
                                                unsigned short* __restrict__ Wpack) {
    int a = blockIdx.x;
    int e = threadIdx.x;
    int kk = e >> 5, hi = (e >> 3) & 3, j = e & 7;
    int ct = a >> 4, lo = a & 15;
    size_t idx = ((size_t)((kk * 16 + ct) * 64 + hi * 16 + lo)) * 8 + j;
    Wpack[idx] = (unsigned short)f2bf(We[(size_t)e * AA + a]);
}

// K1: dec_proj (tiny fp32)
__global__ __launch_bounds__(256) void k_decproj(const float* __restrict__ h,
                                                 const float* __restrict__ Wd,
                                                 float* __restrict__ dp) {
    int b = blockIdx.x;
    int a = threadIdx.x;
    float acc = 0.f;
    for (int e = 0; e < DHH; ++e)
        acc = fmaf(h[b * DHH + e], Wd[e * AA + a], acc);
    dp[b * AA + a] = acc;
}

// K2: fused energy GEMM + local softmax stats + partial context.
// SINGLE-BARRIER structure: phase 1 stages the whole 32x512 A-tile (issue all 16
// loads at once -> one pipelined HBM latency), ONE __syncthreads, phase 2 is the
// entire MFMA loop with zero barriers (B prefetches never force-drained).
// Cross-block TLP (4 blocks/CU) hides phase-1 latency under other blocks' phase 2.
__global__ __launch_bounds__(256, 4) void k_energy_mfma(const float* __restrict__ enc,
                                                        const unsigned short* __restrict__ Wpack,
                                                        const float* __restrict__ dp,
                                                        const float* __restrict__ v,
                                                        const int* __restrict__ mask,
                                                        float* __restrict__ energy,
                                                        float* __restrict__ pctx,
                                                        float2* __restrict__ ml) {
    __shared__ unsigned short Abuf[8][32 * 64];   // 32 KB, swizzled bf16
    __shared__ float part[4][32];
    __shared__ float wbuf[32];

    int bk = blockIdx.x;            // 4096 = 32 b * 128 chunks
    int b  = bk >> 7;
    int chunk = bk & 127;
    int s0 = chunk * 32;
    int tid = threadIdx.x;
    int l  = tid & 63;
    int w  = tid >> 6;
    int lo = l & 15;
    int hi = l >> 4;

    // staging: thread -> row r (0..31), 8-float group q (0..7), all 8 regions
    int r = tid >> 3;
    int q = tid & 7;
    const float* gbase = enc + ((size_t)b * SS + s0 + r) * EHH + q * 8;
    int wb0 = ((r * 128 + q * 16) ^ ((r & 7) << 4));

    // ---- phase 1: issue ALL A-loads, then cvt+write all 8 regions, 1 barrier ----
    float4 sva[8], svb[8];
    #pragma unroll
    for (int kt = 0; kt < 8; ++kt) {
        const float4* gp = (const float4*)(gbase + kt * 64);
        sva[kt] = gp[0]; svb[kt] = gp[1];
    }
    #pragma unroll
    for (int kt = 0; kt < 8; ++kt) {
        uint4 w0 = { cvt2bf(sva[kt].x, sva[kt].y), cvt2bf(sva[kt].z, sva[kt].w),
                     cvt2bf(svb[kt].x, svb[kt].y), cvt2bf(svb[kt].z, svb[kt].w) };
        *(uint4*)((char*)Abuf[kt] + wb0) = w0;
    }
    __syncthreads();

    // ---- phase 2: barrier-free MFMA loop, B 2-deep prefetch from L2 ----
    f32x4 acc[2][4];
    #pragma unroll
    for (int rt = 0; rt < 2; ++rt)
        #pragma unroll
        for (int ct = 0; ct < 4; ++ct)
            acc[rt][ct] = (f32x4){0.f, 0.f, 0.f, 0.f};

    const unsigned short* bbase = Wpack + ((size_t)(w * 4) * 64 + l) * 8;  // + g*8192 + ct*512
    bf16x8 bn0[4], bn1[4];
    #pragma unroll
    for (int ct = 0; ct < 4; ++ct) bn0[ct] = *(const bf16x8*)(bbase + ct * 512);
    #pragma unroll
    for (int ct = 0; ct < 4; ++ct) bn1[ct] = *(const bf16x8*)(bbase + 8192 + ct * 512);

    #pragma unroll
    for (int g = 0; g < 16; ++g) {          // g = kt*2 + ks
        int kt = g >> 1, ks = g & 1;
        bf16x8 bcur[4];
        #pragma unroll
        for (int ct = 0; ct < 4; ++ct) { bcur[ct] = bn0[ct]; bn0[ct] = bn1[ct]; }
        if (g + 2 < 16) {
            const unsigned short* bp = bbase + (size_t)(g + 2) * 8192;
            #pragma unroll
            for (int ct = 0; ct < 4; ++ct)
                bn1[ct] = *(const bf16x8*)(bp + ct * 512);
        }
        const char* lb = (const char*)Abuf[kt];
        bf16x8 afr[2];
        #pragma unroll
        for (int rt = 0; rt < 2; ++rt) {
            int row = rt * 16 + lo;
            afr[rt] = *(const bf16x8*)(lb + ((row * 128 + ks * 64 + hi * 16) ^ ((row & 7) << 4)));
        }
        #pragma unroll
        for (int rt = 0; rt < 2; ++rt)
            #pragma unroll
            for (int ct = 0; ct < 4; ++ct)
                acc[rt][ct] = __builtin_amdgcn_mfma_f32_16x16x32_bf16(afr[rt], bcur[ct], acc[rt][ct], 0, 0, 0);
    }

    // ---- energy epilogue: per-row sum of v[n]*tanh(acc + dp[n]) ----
    float ps[2][4];
    #pragma unroll
    for (int rt = 0; rt < 2; ++rt)
        #pragma unroll
        for (int rr = 0; rr < 4; ++rr) ps[rt][rr] = 0.f;
    #pragma unroll
    for (int ct = 0; ct < 4; ++ct) {
        int n = w * 64 + ct * 16 + lo;
        float dpv = dp[b * AA + n];
        float vv  = v[n];
        #pragma unroll
        for (int rt = 0; rt < 2; ++rt)
            #pragma unroll
            for (int rr = 0; rr < 4; ++rr)
                ps[rt][rr] += vv * tanh_fast(acc[rt][ct][rr] + dpv);
    }
    #pragma unroll
    for (int off = 1; off < 16; off <<= 1)
        #pragma unroll
        for (int rt = 0; rt < 2; ++rt)
            #pragma unroll
            for (int rr = 0; rr < 4; ++rr)
                ps[rt][rr] += __shfl_xor(ps[rt][rr], off);
    if (lo == 0) {
        #pragma unroll
        for (int rt = 0; rt < 2; ++rt)
            #pragma unroll
            for (int rr = 0; rr < 4; ++rr)
                part[w][rt * 16 + 4 * hi + rr] = ps[rt][rr];
    }
    __syncthreads();

    // ---- local softmax stats + weights (wave 0, lanes 0..31; lane = row s) ----
    if (w == 0 && l < 32) {
        float e = part[0][l] + part[1][l] + part[2][l] + part[3][l];
        energy[(size_t)b * SS + s0 + l] = e;
        int mk = mask[(size_t)b * SS + s0 + l];
        float val = mk ? e : -INFINITY;
        float m = val;
        #pragma unroll
        for (int off = 1; off < 32; off <<= 1) m = fmaxf(m, __shfl_xor(m, off));
        float wgt = (val == -INFINITY) ? 0.f : __expf(val - m);
        float lsum = wgt;
        #pragma unroll
        for (int off = 1; off < 32; off <<= 1) lsum += __shfl_xor(lsum, off);
        wbuf[l] = wgt;
        if (l == 0) ml[(size_t)b * 128 + chunk] = float2{m, lsum};
    }
    __syncthreads();

    // ---- partial context: pctx[e] = sum_s wgt[s] * enc_bf16[s][e] from LDS ----
    {
        int e0 = tid * 2;
        int reg = e0 >> 6;
        int c   = e0 & 63;
        const char* lb = (const char*)Abuf[reg];
        float a0 = 0.f, a1 = 0.f;
        #pragma unroll 8
        for (int s = 0; s < 32; ++s) {
            float wv_ = wbuf[s];
            unsigned u = *(const unsigned*)(lb + ((s * 128 + c * 2) ^ ((s & 7) << 4)));
            float x0 = __uint_as_float(u << 16);
            float x1 = __uint_as_float(u & 0xFFFF0000u);
            a0 = fmaf(wv_, x0, a0);
            a1 = fmaf(wv_, x1, a1);
        }
        *(float2*)&pctx[((size_t)(b * 128 + chunk)) * 512 + e0] = float2{a0, a1};
    }
}

// K3: one-pass masked softmax using per-chunk (m,l) stats. Grid (16 slices, B).
__global__ __launch_bounds__(256) void k_softmax(const float* __restrict__ energy,
                                                 const int* __restrict__ mask,
                                                 const float2* __restrict__ ml,
                                                 float* __restrict__ attn) {
    __shared__ float wm[4], wz[4];
    int b = blockIdx.y;
    int tid = threadIdx.x;
    int l = tid & 63, w = tid >> 6;

    float2 p = float2{-INFINITY, 0.f};
    if (tid < 128) p = ml[(size_t)b * 128 + tid];
    float m = p.x;
    #pragma unroll
    for (int off = 1; off < 64; off <<= 1) m = fmaxf(m, __shfl_xor(m, off));
    if (!l) wm[w] = m;
    __syncthreads();
    float M = fmaxf(fmaxf(wm[0], wm[1]), fmaxf(wm[2], wm[3]));
    float z = (p.x == -INFINITY) ? 0.f : __expf(p.x - M) * p.y;
    #pragma unroll
    for (int off = 1; off < 64; off <<= 1) z += __shfl_xor(z, off);
    if (!l) wz[w] = z;
    __syncthreads();
    float Z = wz[0] + wz[1] + wz[2] + wz[3];
    float invZ = (Z > 0.f) ? 1.0f / Z : 0.f;

    int s = blockIdx.x * 256 + tid;
    float e = energy[(size_t)b * SS + s];
    int mk = mask[(size_t)b * SS + s];
    attn[(size_t)b * SS + s] = mk ? __expf(e - M) * invZ : 0.f;
}

// K4: final context = rescaled sum of 128 chunk partials per batch
__global__ __launch_bounds__(512) void k_ctx_final(const float* __restrict__ pctx,
                                                   const float2* __restrict__ ml,
                                                   float* __restrict__ ctx) {
    __shared__ float scal[128];
    __shared__ float wm[8], wz[8];
    int b = blockIdx.x;
    int tid = threadIdx.x;
    int l = tid & 63, w = tid >> 6;

    float2 p = float2{-INFINITY, 0.f};
    if (tid < 128) p = ml[(size_t)b * 128 + tid];
    float m = p.x;
    #pragma unroll
    for (int off = 1; off < 64; off <<= 1) m = fmaxf(m, __shfl_xor(m, off));
    if (!l) wm[w] = m;
    __syncthreads();
    float M = wm[0];
    #pragma unroll
    for (int i = 1; i < 8; ++i) M = fmaxf(M, wm[i]);
    float sc = (p.x == -INFINITY) ? 0.f : __expf(p.x - M);
    if (tid < 128) scal[tid] = sc;
    float z = sc * p.y;
    #pragma unroll
    for (int off = 1; off < 64; off <<= 1) z += __shfl_xor(z, off);
    if (!l) wz[w] = z;
    __syncthreads();
    float Z = 0.f;
    #pragma unroll
    for (int i = 0; i < 8; ++i) Z += wz[i];
    float invZ = (Z > 0.f) ? 1.0f / Z : 0.f;

    float acc = 0.f;
    #pragma unroll 8
    for (int c = 0; c < 128; ++c)
        acc = fmaf(scal[c], pctx[((size_t)(b * 128 + c)) * 512 + tid], acc);
    ctx[(size_t)b * EHH + tid] = acc * invZ;
}

extern "C" void kernel_launch(void* const* d_in, const int* in_sizes, int n_in,
                              void* d_out, int out_size, void* d_ws, size_t ws_size,
                              hipStream_t stream) {
    const float* h    = (const float*)d_in[0];
    const float* enc  = (const float*)d_in[1];
    const int*   mask = (const int*)d_in[2];
    const float* Wd   = (const float*)d_in[3];
    const float* We   = (const float*)d_in[4];
    const float* v    = (const float*)d_in[5];

    float* out  = (float*)d_out;
    float* ctx  = out;              // (B, EH)
    float* attn = out + BB * EHH;   // (B, S)

    char* ws = (char*)d_ws;
    float*          dp     = (float*)ws;                          // 32 KB
    float*          energy = (float*)(ws + (32 << 10));           // 512 KB
    unsigned short* Wpack  = (unsigned short*)(ws + (576 << 10)); // 256 KB
    float*          pctx   = (float*)(ws + (1 << 20));            // 8 MB
    float2*         ml     = (float2*)(ws + (9 << 20));           // 32 KB

    k_packWe<<<AA, 512, 0, stream>>>(We, Wpack);
    k_decproj<<<BB, AA, 0, stream>>>(h, Wd, dp);
    k_energy_mfma<<<BB * SS / 32, 256, 0, stream>>>(enc, Wpack, dp, v, mask,
                                                    energy, pctx, ml);
    k_softmax<<<dim3(16, BB), 256, 0, stream>>>(energy, mask, ml, attn);
    k_ctx_final<<<BB, 512, 0, stream>>>(pctx, ml, ctx);
}

// Round 9
// 95.655 us; speedup vs baseline: 7.5783x; 1.2609x over previous
//
#include <hip/hip_runtime.h>
#include <hip/hip_bf16.h>
#include <math.h>

#define BB 32
#define SS 4096
#define DHH 512
#define EHH 512
#define AA 256

typedef __attribute__((ext_vector_type(8))) short bf16x8;
typedef __attribute__((ext_vector_type(4))) float f32x4;

__device__ __forceinline__ short f2bf(float f) {
    unsigned u = __float_as_uint(f);
    u += 0x7FFFu + ((u >> 16) & 1u);   // RNE
    return (short)(u >> 16);
}

__device__ __forceinline__ unsigned cvt2bf(float a, float b) {
    __hip_bfloat162 h = __float22bfloat162_rn(float2{a, b});  // v_cvt_pk_bf16_f32
    return *(unsigned*)&h;
}

__device__ __forceinline__ float tanh_fast(float x) {
    float e = __expf(2.0f * x);
    return 1.0f - 2.0f * __builtin_amdgcn_rcpf(e + 1.0f);
}

// K0: pack We (E,A) fp32 -> fragment-major bf16, COALESCED reads.
// Wpack[((kk*16 + ct)*64 + hi*16 + lo)*8 + j] = We[k][n], k = kk*32+hi*8+j, n = ct*16+lo
// Block covers 4 e-rows x 256 a: thread (tid>>6) = row offset, (tid&63)*4 = a base.
__global__ __launch_bounds__(256) void k_packWe(const float* __restrict__ We,
                                                unsigned short* __restrict__ Wpack) {
    int tid = threadIdx.x;
    int e = blockIdx.x * 4 + (tid >> 6);     // 128 blocks
    int a4 = (tid & 63) * 4;
    float4 t = *(const float4*)&We[(size_t)e * AA + a4];
    int kk = e >> 5, hi = (e >> 3) & 3, j = e & 7;
    const float* tf = (const float*)&t;
    #pragma unroll
    for (int u = 0; u < 4; ++u) {
        int a = a4 + u;
        int ct = a >> 4, lo = a & 15;
        Wpack[((size_t)((kk * 16 + ct) * 64 + hi * 16 + lo)) * 8 + j] = (unsigned short)f2bf(tf[u]);
    }
}

// K1: dec_proj partials, 8-way K-split: dp8[b][sp][a] = sum_{e in split} h[b][e]*Wd[e][a]
__global__ __launch_bounds__(256) void k_decproj(const float* __restrict__ h,
                                                 const float* __restrict__ Wd,
                                                 float* __restrict__ dp8) {
    int b = blockIdx.x, sp = blockIdx.y;
    int a = threadIdx.x;
    const float* hb = h + (size_t)b * DHH + sp * 64;
    const float* wb = Wd + (size_t)(sp * 64) * AA + a;
    float acc = 0.f;
    #pragma unroll 16
    for (int i = 0; i < 64; ++i)
        acc = fmaf(hb[i], wb[(size_t)i * AA], acc);
    dp8[((size_t)b * 8 + sp) * AA + a] = acc;
}

// K2: fused energy GEMM + local softmax stats + partial context.
// Single-barrier staging (R8 structure, unchanged core), dp read as 8 partials.
__global__ __launch_bounds__(256, 4) void k_energy_mfma(const float* __restrict__ enc,
                                                        const unsigned short* __restrict__ Wpack,
                                                        const float* __restrict__ dp8,
                                                        const float* __restrict__ v,
                                                        const int* __restrict__ mask,
                                                        float* __restrict__ energy,
                                                        float* __restrict__ pctx,
                                                        float2* __restrict__ ml) {
    __shared__ unsigned short Abuf[8][32 * 64];   // 32 KB, swizzled bf16
    __shared__ float part[4][32];
    __shared__ float wbuf[32];

    int bk = blockIdx.x;            // 4096 = 32 b * 128 chunks
    int b  = bk >> 7;
    int chunk = bk & 127;
    int s0 = chunk * 32;
    int tid = threadIdx.x;
    int l  = tid & 63;
    int w  = tid >> 6;
    int lo = l & 15;
    int hi = l >> 4;

    int r = tid >> 3;
    int q = tid & 7;
    const float* gbase = enc + ((size_t)b * SS + s0 + r) * EHH + q * 8;
    int wb0 = ((r * 128 + q * 16) ^ ((r & 7) << 4));

    // ---- phase 1: issue ALL A-loads, cvt+write all 8 regions, 1 barrier ----
    float4 sva[8], svb[8];
    #pragma unroll
    for (int kt = 0; kt < 8; ++kt) {
        const float4* gp = (const float4*)(gbase + kt * 64);
        sva[kt] = gp[0]; svb[kt] = gp[1];
    }
    #pragma unroll
    for (int kt = 0; kt < 8; ++kt) {
        uint4 w0 = { cvt2bf(sva[kt].x, sva[kt].y), cvt2bf(sva[kt].z, sva[kt].w),
                     cvt2bf(svb[kt].x, svb[kt].y), cvt2bf(svb[kt].z, svb[kt].w) };
        *(uint4*)((char*)Abuf[kt] + wb0) = w0;
    }
    __syncthreads();

    // ---- phase 2: barrier-free MFMA loop, B 2-deep prefetch from L2 ----
    f32x4 acc[2][4];
    #pragma unroll
    for (int rt = 0; rt < 2; ++rt)
        #pragma unroll
        for (int ct = 0; ct < 4; ++ct)
            acc[rt][ct] = (f32x4){0.f, 0.f, 0.f, 0.f};

    const unsigned short* bbase = Wpack + ((size_t)(w * 4) * 64 + l) * 8;
    bf16x8 bn0[4], bn1[4];
    #pragma unroll
    for (int ct = 0; ct < 4; ++ct) bn0[ct] = *(const bf16x8*)(bbase + ct * 512);
    #pragma unroll
    for (int ct = 0; ct < 4; ++ct) bn1[ct] = *(const bf16x8*)(bbase + 8192 + ct * 512);

    #pragma unroll
    for (int g = 0; g < 16; ++g) {          // g = kt*2 + ks
        int kt = g >> 1, ks = g & 1;
        bf16x8 bcur[4];
        #pragma unroll
        for (int ct = 0; ct < 4; ++ct) { bcur[ct] = bn0[ct]; bn0[ct] = bn1[ct]; }
        if (g + 2 < 16) {
            const unsigned short* bp = bbase + (size_t)(g + 2) * 8192;
            #pragma unroll
            for (int ct = 0; ct < 4; ++ct)
                bn1[ct] = *(const bf16x8*)(bp + ct * 512);
        }
        const char* lb = (const char*)Abuf[kt];
        bf16x8 afr[2];
        #pragma unroll
        for (int rt = 0; rt < 2; ++rt) {
            int row = rt * 16 + lo;
            afr[rt] = *(const bf16x8*)(lb + ((row * 128 + ks * 64 + hi * 16) ^ ((row & 7) << 4)));
        }
        #pragma unroll
        for (int rt = 0; rt < 2; ++rt)
            #pragma unroll
            for (int ct = 0; ct < 4; ++ct)
                acc[rt][ct] = __builtin_amdgcn_mfma_f32_16x16x32_bf16(afr[rt], bcur[ct], acc[rt][ct], 0, 0, 0);
    }

    // ---- energy epilogue ----
    float ps[2][4];
    #pragma unroll
    for (int rt = 0; rt < 2; ++rt)
        #pragma unroll
        for (int rr = 0; rr < 4; ++rr) ps[rt][rr] = 0.f;
    #pragma unroll
    for (int ct = 0; ct < 4; ++ct) {
        int n = w * 64 + ct * 16 + lo;
        float dpv = 0.f;
        #pragma unroll
        for (int sp = 0; sp < 8; ++sp)
            dpv += dp8[((size_t)b * 8 + sp) * AA + n];
        float vv = v[n];
        #pragma unroll
        for (int rt = 0; rt < 2; ++rt)
            #pragma unroll
            for (int rr = 0; rr < 4; ++rr)
                ps[rt][rr] += vv * tanh_fast(acc[rt][ct][rr] + dpv);
    }
    #pragma unroll
    for (int off = 1; off < 16; off <<= 1)
        #pragma unroll
        for (int rt = 0; rt < 2; ++rt)
            #pragma unroll
            for (int rr = 0; rr < 4; ++rr)
                ps[rt][rr] += __shfl_xor(ps[rt][rr], off);
    if (lo == 0) {
        #pragma unroll
        for (int rt = 0; rt < 2; ++rt)
            #pragma unroll
            for (int rr = 0; rr < 4; ++rr)
                part[w][rt * 16 + 4 * hi + rr] = ps[rt][rr];
    }
    __syncthreads();

    // ---- local softmax stats + weights (wave 0, lanes 0..31) ----
    if (w == 0 && l < 32) {
        float e = part[0][l] + part[1][l] + part[2][l] + part[3][l];
        energy[(size_t)b * SS + s0 + l] = e;
        int mk = mask[(size_t)b * SS + s0 + l];
        float val = mk ? e : -INFINITY;
        float m = val;
        #pragma unroll
        for (int off = 1; off < 32; off <<= 1) m = fmaxf(m, __shfl_xor(m, off));
        float wgt = (val == -INFINITY) ? 0.f : __expf(val - m);
        float lsum = wgt;
        #pragma unroll
        for (int off = 1; off < 32; off <<= 1) lsum += __shfl_xor(lsum, off);
        wbuf[l] = wgt;
        if (l == 0) ml[(size_t)b * 128 + chunk] = float2{m, lsum};
    }
    __syncthreads();

    // ---- partial context from LDS ----
    {
        int e0 = tid * 2;
        int reg = e0 >> 6;
        int c   = e0 & 63;
        const char* lb = (const char*)Abuf[reg];
        float a0 = 0.f, a1 = 0.f;
        #pragma unroll 8
        for (int s = 0; s < 32; ++s) {
            float wv_ = wbuf[s];
            unsigned u = *(const unsigned*)(lb + ((s * 128 + c * 2) ^ ((s & 7) << 4)));
            float x0 = __uint_as_float(u << 16);
            float x1 = __uint_as_float(u & 0xFFFF0000u);
            a0 = fmaf(wv_, x0, a0);
            a1 = fmaf(wv_, x1, a1);
        }
        *(float2*)&pctx[((size_t)(b * 128 + chunk)) * 512 + e0] = float2{a0, a1};
    }
}

// K3: fused final softmax (attn) + context. Grid (B, 4 slices), 512 thr.
// Slice sl: attn rows sl*1024..+1024, ctx cols sl*128..+128.
__global__ __launch_bounds__(512) void k_final(const float* __restrict__ energy,
                                               const int* __restrict__ mask,
                                               const float2* __restrict__ ml,
                                               const float* __restrict__ pctx,
                                               float* __restrict__ attn,
                                               float* __restrict__ ctx) {
    __shared__ float wm[8], wz[8];
    __shared__ float red[4][128];
    int b = blockIdx.x, sl = blockIdx.y;
    int tid = threadIdx.x;
    int l = tid & 63, w = tid >> 6;

    float2 p = float2{-INFINITY, 0.f};
    if (tid < 128) p = ml[(size_t)b * 128 + tid];
    float m = p.x;
    #pragma unroll
    for (int off = 1; off < 64; off <<= 1) m = fmaxf(m, __shfl_xor(m, off));
    if (!l) wm[w] = m;
    __syncthreads();
    float M = wm[0];
    #pragma unroll
    for (int i = 1; i < 8; ++i) M = fmaxf(M, wm[i]);
    float z = (p.x == -INFINITY) ? 0.f : __expf(p.x - M) * p.y;
    #pragma unroll
    for (int off = 1; off < 64; off <<= 1) z += __shfl_xor(z, off);
    if (!l) wz[w] = z;
    __syncthreads();
    float Z = 0.f;
    #pragma unroll
    for (int i = 0; i < 8; ++i) Z += wz[i];
    float invZ = (Z > 0.f) ? 1.0f / Z : 0.f;

    // attn slice: 2 iters of 512
    #pragma unroll
    for (int it = 0; it < 2; ++it) {
        int s = sl * 1024 + it * 512 + tid;
        float e = energy[(size_t)b * SS + s];
        int mk = mask[(size_t)b * SS + s];
        attn[(size_t)b * SS + s] = mk ? __expf(e - M) * invZ : 0.f;
    }

    // ctx slice: 4 groups of 128 threads each cover 32 chunks, LDS-reduce
    {
        int cg = tid >> 7;            // 0..3
        int e  = sl * 128 + (tid & 127);
        float acc = 0.f;
        #pragma unroll 8
        for (int i = 0; i < 32; ++i) {
            int c = cg * 32 + i;
            float2 pc = ml[(size_t)b * 128 + c];
            float sc = (pc.x == -INFINITY) ? 0.f : __expf(pc.x - M);
            acc = fmaf(sc, pctx[((size_t)(b * 128 + c)) * 512 + e], acc);
        }
        red[cg][tid & 127] = acc;
    }
    __syncthreads();
    if (tid < 128) {
        float s = red[0][tid] + red[1][tid] + red[2][tid] + red[3][tid];
        ctx[(size_t)b * EHH + sl * 128 + tid] = s * invZ;
    }
}

extern "C" void kernel_launch(void* const* d_in, const int* in_sizes, int n_in,
                              void* d_out, int out_size, void* d_ws, size_t ws_size,
                              hipStream_t stream) {
    const float* h    = (const float*)d_in[0];
    const float* enc  = (const float*)d_in[1];
    const int*   mask = (const int*)d_in[2];
    const float* Wd   = (const float*)d_in[3];
    const float* We   = (const float*)d_in[4];
    const float* v    = (const float*)d_in[5];

    float* out  = (float*)d_out;
    float* ctx  = out;              // (B, EH)
    float* attn = out + BB * EHH;   // (B, S)

    char* ws = (char*)d_ws;
    float*          dp8    = (float*)ws;                          // 256 KB
    float*          energy = (float*)(ws + (256 << 10));          // 512 KB
    unsigned short* Wpack  = (unsigned short*)(ws + (768 << 10)); // 256 KB
    float*          pctx   = (float*)(ws + (1 << 20));            // 8 MB
    float2*         ml     = (float2*)(ws + (9 << 20));           // 32 KB

    k_packWe<<<128, 256, 0, stream>>>(We, Wpack);
    k_decproj<<<dim3(BB, 8), AA, 0, stream>>>(h, Wd, dp8);
    k_energy_mfma<<<BB * SS / 32, 256, 0, stream>>>(enc, Wpack, dp8, v, mask,
                                                    energy, pctx, ml);
    k_final<<<dim3(BB, 4), 512, 0, stream>>>(energy, mask, ml, pctx, attn, ctx);
}

// Round 10
// 95.075 us; speedup vs baseline: 7.6246x; 1.0061x over previous
//
#include <hip/hip_runtime.h>
#include <hip/hip_bf16.h>
#include <math.h>

#define BB 32
#define SS 4096
#define DHH 512
#define EHH 512
#define AA 256

typedef __attribute__((ext_vector_type(8))) short bf16x8;
typedef __attribute__((ext_vector_type(4))) float f32x4;

__device__ __forceinline__ short f2bf(float f) {
    unsigned u = __float_as_uint(f);
    u += 0x7FFFu + ((u >> 16) & 1u);   // RNE
    return (short)(u >> 16);
}

__device__ __forceinline__ unsigned cvt2bf(float a, float b) {
    __hip_bfloat162 h = __float22bfloat162_rn(float2{a, b});  // v_cvt_pk_bf16_f32
    return *(unsigned*)&h;
}

__device__ __forceinline__ float tanh_fast(float x) {
    float e = __expf(2.0f * x);
    return 1.0f - 2.0f * __builtin_amdgcn_rcpf(e + 1.0f);
}

// K0: pack We (E,A) fp32 -> fragment-major bf16, coalesced reads.
// Wpack[((kk*16 + ct)*64 + hi*16 + lo)*8 + j] = We[k][n], k = kk*32+hi*8+j, n = ct*16+lo
__global__ __launch_bounds__(256) void k_packWe(const float* __restrict__ We,
                                                unsigned short* __restrict__ Wpack) {
    int tid = threadIdx.x;
    int e = blockIdx.x * 4 + (tid >> 6);     // 128 blocks
    int a4 = (tid & 63) * 4;
    float4 t = *(const float4*)&We[(size_t)e * AA + a4];
    int kk = e >> 5, hi = (e >> 3) & 3, j = e & 7;
    const float* tf = (const float*)&t;
    #pragma unroll
    for (int u = 0; u < 4; ++u) {
        int a = a4 + u;
        int ct = a >> 4, lo = a & 15;
        Wpack[((size_t)((kk * 16 + ct) * 64 + hi * 16 + lo)) * 8 + j] = (unsigned short)f2bf(tf[u]);
    }
}

// K1: dec_proj partials, 8-way K-split
__global__ __launch_bounds__(256) void k_decproj(const float* __restrict__ h,
                                                 const float* __restrict__ Wd,
                                                 float* __restrict__ dp8) {
    int b = blockIdx.x, sp = blockIdx.y;
    int a = threadIdx.x;
    const float* hb = h + (size_t)b * DHH + sp * 64;
    const float* wb = Wd + (size_t)(sp * 64) * AA + a;
    float acc = 0.f;
    #pragma unroll 16
    for (int i = 0; i < 64; ++i)
        acc = fmaf(hb[i], wb[(size_t)i * AA], acc);
    dp8[((size_t)b * 8 + sp) * AA + a] = acc;
}

// K2: fused energy GEMM + local softmax stats + partial context.
// 64-row chunks, 512 thr (8 waves). Wave w: ALL 64 rows (rt 0..3), cols w*32..+32
// (ct 0..1) -> B traffic per block unchanged vs 32-row => total HALVED (2048 blocks).
// LDS 64KB+2KB -> 2 blocks/CU x 8 waves = 16 waves/CU (same as R9's 4x4).
// Single-barrier staging; B 2-deep register prefetch from L2.
__global__ __launch_bounds__(512, 4) void k_energy_mfma(const float* __restrict__ enc,
                                                        const unsigned short* __restrict__ Wpack,
                                                        const float* __restrict__ dp8,
                                                        const float* __restrict__ v,
                                                        const int* __restrict__ mask,
                                                        float* __restrict__ energy,
                                                        float* __restrict__ pctx,
                                                        float2* __restrict__ ml) {
    __shared__ unsigned short Abuf[8][64 * 64];   // 64 KB, swizzled bf16
    __shared__ float part[8][64];                 // 2 KB
    __shared__ float wbuf[64];

    int bk = blockIdx.x;            // 2048 = 32 b * 64 chunks
    int b  = bk >> 6;
    int chunk = bk & 63;
    int s0 = chunk * 64;
    int tid = threadIdx.x;
    int l  = tid & 63;
    int w  = tid >> 6;              // 0..7
    int lo = l & 15;
    int hi = l >> 4;

    // staging: thread -> row r (0..63), 8-float group q (0..7), all 8 regions
    int r = tid >> 3;
    int q = tid & 7;
    const float* gbase = enc + ((size_t)b * SS + s0 + r) * EHH + q * 8;
    int wb0 = ((r * 128 + q * 16) ^ ((r & 7) << 4));

    // ---- phase 1: issue ALL A-loads, cvt+write all 8 regions, 1 barrier ----
    float4 sva[8], svb[8];
    #pragma unroll
    for (int kt = 0; kt < 8; ++kt) {
        const float4* gp = (const float4*)(gbase + kt * 64);
        sva[kt] = gp[0]; svb[kt] = gp[1];
    }
    #pragma unroll
    for (int kt = 0; kt < 8; ++kt) {
        uint4 w0 = { cvt2bf(sva[kt].x, sva[kt].y), cvt2bf(sva[kt].z, sva[kt].w),
                     cvt2bf(svb[kt].x, svb[kt].y), cvt2bf(svb[kt].z, svb[kt].w) };
        *(uint4*)((char*)Abuf[kt] + wb0) = w0;
    }
    __syncthreads();

    // ---- phase 2: barrier-free MFMA loop, B 2-deep prefetch from L2 ----
    f32x4 acc[4][2];
    #pragma unroll
    for (int rt = 0; rt < 4; ++rt)
        #pragma unroll
        for (int ct = 0; ct < 2; ++ct)
            acc[rt][ct] = (f32x4){0.f, 0.f, 0.f, 0.f};

    const unsigned short* bbase = Wpack + ((size_t)(w * 2) * 64 + l) * 8;  // + g*8192 + ct*512
    bf16x8 bn0[2], bn1[2];
    #pragma unroll
    for (int ct = 0; ct < 2; ++ct) bn0[ct] = *(const bf16x8*)(bbase + ct * 512);
    #pragma unroll
    for (int ct = 0; ct < 2; ++ct) bn1[ct] = *(const bf16x8*)(bbase + 8192 + ct * 512);

    #pragma unroll
    for (int g = 0; g < 16; ++g) {          // g = kt*2 + ks
        int kt = g >> 1, ks = g & 1;
        bf16x8 bcur[2];
        #pragma unroll
        for (int ct = 0; ct < 2; ++ct) { bcur[ct] = bn0[ct]; bn0[ct] = bn1[ct]; }
        if (g + 2 < 16) {
            const unsigned short* bp = bbase + (size_t)(g + 2) * 8192;
            #pragma unroll
            for (int ct = 0; ct < 2; ++ct)
                bn1[ct] = *(const bf16x8*)(bp + ct * 512);
        }
        const char* lb = (const char*)Abuf[kt];
        bf16x8 afr[4];
        #pragma unroll
        for (int rt = 0; rt < 4; ++rt) {
            int row = rt * 16 + lo;
            afr[rt] = *(const bf16x8*)(lb + ((row * 128 + ks * 64 + hi * 16) ^ ((row & 7) << 4)));
        }
        #pragma unroll
        for (int rt = 0; rt < 4; ++rt)
            #pragma unroll
            for (int ct = 0; ct < 2; ++ct)
                acc[rt][ct] = __builtin_amdgcn_mfma_f32_16x16x32_bf16(afr[rt], bcur[ct], acc[rt][ct], 0, 0, 0);
    }

    // ---- energy epilogue: ps[rt][rr] = partial row-sum over this wave's 32 cols ----
    float ps[4][4];
    #pragma unroll
    for (int rt = 0; rt < 4; ++rt)
        #pragma unroll
        for (int rr = 0; rr < 4; ++rr) ps[rt][rr] = 0.f;
    #pragma unroll
    for (int ct = 0; ct < 2; ++ct) {
        int n = w * 32 + ct * 16 + lo;
        float dpv = 0.f;
        #pragma unroll
        for (int sp = 0; sp < 8; ++sp)
            dpv += dp8[((size_t)b * 8 + sp) * AA + n];
        float vv = v[n];
        #pragma unroll
        for (int rt = 0; rt < 4; ++rt)
            #pragma unroll
            for (int rr = 0; rr < 4; ++rr)
                ps[rt][rr] += vv * tanh_fast(acc[rt][ct][rr] + dpv);
    }
    #pragma unroll
    for (int off = 1; off < 16; off <<= 1)
        #pragma unroll
        for (int rt = 0; rt < 4; ++rt)
            #pragma unroll
            for (int rr = 0; rr < 4; ++rr)
                ps[rt][rr] += __shfl_xor(ps[rt][rr], off);
    if (lo == 0) {
        #pragma unroll
        for (int rt = 0; rt < 4; ++rt)
            #pragma unroll
            for (int rr = 0; rr < 4; ++rr)
                part[w][rt * 16 + 4 * hi + rr] = ps[rt][rr];
    }
    __syncthreads();

    // ---- local softmax stats + weights (wave 0; lane = row s, 64 rows) ----
    if (w == 0) {
        float e = 0.f;
        #pragma unroll
        for (int i = 0; i < 8; ++i) e += part[i][l];
        energy[(size_t)b * SS + s0 + l] = e;
        int mk = mask[(size_t)b * SS + s0 + l];
        float val = mk ? e : -INFINITY;
        float m = val;
        #pragma unroll
        for (int off = 1; off < 64; off <<= 1) m = fmaxf(m, __shfl_xor(m, off));
        float wgt = (val == -INFINITY) ? 0.f : __expf(val - m);
        float lsum = wgt;
        #pragma unroll
        for (int off = 1; off < 64; off <<= 1) lsum += __shfl_xor(lsum, off);
        wbuf[l] = wgt;
        if (l == 0) ml[(size_t)b * 64 + chunk] = float2{m, lsum};
    }
    __syncthreads();

    // ---- partial context: pctx[e] = sum_s wgt[s] * enc_bf16[s][e] (1 col/thread) ----
    {
        int e = tid;                 // 0..511
        int reg = e >> 6;
        int c2 = (e & 63) * 2;       // byte col offset
        const char* lb = (const char*)Abuf[reg];
        float a0 = 0.f;
        #pragma unroll 8
        for (int s = 0; s < 64; ++s) {
            float wv_ = wbuf[s];
            unsigned short u = *(const unsigned short*)(lb + ((s * 128 + c2) ^ ((s & 7) << 4)));
            a0 = fmaf(wv_, __uint_as_float(((unsigned)u) << 16), a0);
        }
        pctx[((size_t)(b * 64 + chunk)) * 512 + e] = a0;
    }
}

// K3: fused final softmax (attn) + context. Grid (B, 4 slices), 512 thr.
__global__ __launch_bounds__(512) void k_final(const float* __restrict__ energy,
                                               const int* __restrict__ mask,
                                               const float2* __restrict__ ml,
                                               const float* __restrict__ pctx,
                                               float* __restrict__ attn,
                                               float* __restrict__ ctx) {
    __shared__ float scal[64];
    __shared__ float sM, sZ;
    __shared__ float red[4][128];
    int b = blockIdx.x, sl = blockIdx.y;
    int tid = threadIdx.x;

    if (tid < 64) {                 // wave 0: chunk stats (64 chunks)
        float2 p = ml[(size_t)b * 64 + tid];
        float m = p.x;
        #pragma unroll
        for (int off = 1; off < 64; off <<= 1) m = fmaxf(m, __shfl_xor(m, off));
        float sc = (p.x == -INFINITY) ? 0.f : __expf(p.x - m);
        scal[tid] = sc;
        float z = sc * p.y;
        #pragma unroll
        for (int off = 1; off < 64; off <<= 1) z += __shfl_xor(z, off);
        if (tid == 0) { sM = m; sZ = z; }
    }
    __syncthreads();
    float M = sM;
    float invZ = (sZ > 0.f) ? 1.0f / sZ : 0.f;

    // attn slice: 2 iters of 512
    #pragma unroll
    for (int it = 0; it < 2; ++it) {
        int s = sl * 1024 + it * 512 + tid;
        float e = energy[(size_t)b * SS + s];
        int mk = mask[(size_t)b * SS + s];
        attn[(size_t)b * SS + s] = mk ? __expf(e - M) * invZ : 0.f;
    }

    // ctx slice: 4 groups of 128 threads, each covers 16 chunks, LDS-reduce
    {
        int cg = tid >> 7;            // 0..3
        int e  = sl * 128 + (tid & 127);
        float acc = 0.f;
        #pragma unroll 8
        for (int i = 0; i < 16; ++i) {
            int c = cg * 16 + i;
            acc = fmaf(scal[c], pctx[((size_t)(b * 64 + c)) * 512 + e], acc);
        }
        red[cg][tid & 127] = acc;
    }
    __syncthreads();
    if (tid < 128) {
        float s = red[0][tid] + red[1][tid] + red[2][tid] + red[3][tid];
        ctx[(size_t)b * EHH + sl * 128 + tid] = s * invZ;
    }
}

extern "C" void kernel_launch(void* const* d_in, const int* in_sizes, int n_in,
                              void* d_out, int out_size, void* d_ws, size_t ws_size,
                              hipStream_t stream) {
    const float* h    = (const float*)d_in[0];
    const float* enc  = (const float*)d_in[1];
    const int*   mask = (const int*)d_in[2];
    const float* Wd   = (const float*)d_in[3];
    const float* We   = (const float*)d_in[4];
    const float* v    = (const float*)d_in[5];

    float* out  = (float*)d_out;
    float* ctx  = out;              // (B, EH)
    float* attn = out + BB * EHH;   // (B, S)

    char* ws = (char*)d_ws;
    float*          dp8    = (float*)ws;                          // 256 KB
    float*          energy = (float*)(ws + (256 << 10));          // 512 KB
    unsigned short* Wpack  = (unsigned short*)(ws + (768 << 10)); // 256 KB
    float*          pctx   = (float*)(ws + (1 << 20));            // 4 MB
    float2*         ml     = (float2*)(ws + (6 << 20));           // 16 KB

    k_packWe<<<128, 256, 0, stream>>>(We, Wpack);
    k_decproj<<<dim3(BB, 8), AA, 0, stream>>>(h, Wd, dp8);
    k_energy_mfma<<<BB * SS / 64, 512, 0, stream>>>(enc, Wpack, dp8, v, mask,
                                                    energy, pctx, ml);
    k_final<<<dim3(BB, 4), 512, 0, stream>>>(energy, mask, ml, pctx, attn, ctx);
}